// Round 1
// baseline (9326.672 us; speedup 1.0000x reference)
//
#include <hip/hip_runtime.h>
#include <cstddef>
#include <cstdint>

// ---------------- problem constants ----------------
#define C_DIM   1536
#define L_SEQ   2400
#define L_CTX   512
#define N_HEADS 12
#define D_HEAD  128
#define FF_DIM  8960
#define F_GRID  2
#define H_GRID  30
#define W_GRID  40
#define EPS_F   1e-6f

// rope band boundaries over D/2=64 pairs: p0=22 (frame), p1=21 (height), rest (width)
#define ROPE_P0 22
#define ROPE_P1 43   // p0 + p1

// ---------------- small elementwise kernels ----------------

// ev[i] = modulation[i] + e[i], i < 6*C
__global__ __launch_bounds__(256) void k_embed(const float* __restrict__ mod,
                                               const float* __restrict__ e,
                                               float* __restrict__ ev, int n) {
    int i = blockIdx.x * 256 + threadIdx.x;
    if (i < n) ev[i] = mod[i] + e[i];
}

// out[i] = a[i] + b[i] * (ei>=0 ? ev[ei*C + i%C] : 1)
__global__ __launch_bounds__(256) void k_resid(const float* __restrict__ a,
                                               const float* __restrict__ b,
                                               const float* __restrict__ ev, int ei,
                                               float* __restrict__ out, int n) {
    int i = blockIdx.x * 256 + threadIdx.x;
    if (i >= n) return;
    float s = (ei >= 0) ? ev[ei * C_DIM + (i % C_DIM)] : 1.0f;
    out[i] = a[i] + b[i] * s;
}

// in-place tanh-approx gelu
__global__ __launch_bounds__(256) void k_gelu(float* __restrict__ x, int n) {
    int i = blockIdx.x * 256 + threadIdx.x;
    if (i >= n) return;
    float v = x[i];
    float t = tanhf(0.7978845608028654f * (v + 0.044715f * v * v * v));
    x[i] = 0.5f * v * (1.0f + t);
}

// ---------------- LayerNorm + modulation ----------------
// h[row] = ev[i0] + LN(x[row]) * (1 + ev[i1]); one block per row, 256 thr, 6 elem/thr
__global__ __launch_bounds__(256) void k_lnmod(const float* __restrict__ X,
                                               const float* __restrict__ ev,
                                               int i0, int i1,
                                               float* __restrict__ H) {
    __shared__ float rs[256];
    __shared__ float rs2[256];
    int row = blockIdx.x, tid = threadIdx.x;
    const float* xr = X + (size_t)row * C_DIM;
    float vals[6];
    float s = 0.f, s2 = 0.f;
#pragma unroll
    for (int i = 0; i < 6; ++i) {
        float v = xr[tid + 256 * i];
        vals[i] = v; s += v; s2 += v * v;
    }
    rs[tid] = s; rs2[tid] = s2;
    __syncthreads();
    for (int st = 128; st > 0; st >>= 1) {
        if (tid < st) { rs[tid] += rs[tid + st]; rs2[tid] += rs2[tid + st]; }
        __syncthreads();
    }
    float mean = rs[0] * (1.0f / C_DIM);
    float var  = rs2[0] * (1.0f / C_DIM) - mean * mean;
    float rinv = rsqrtf(var + EPS_F);
    const float* E0 = ev + (size_t)i0 * C_DIM;
    const float* E1 = ev + (size_t)i1 * C_DIM;
    float* hr = H + (size_t)row * C_DIM;
#pragma unroll
    for (int i = 0; i < 6; ++i) {
        int c = tid + 256 * i;
        hr[c] = E0[c] + (vals[i] - mean) * rinv * (1.0f + E1[c]);
    }
}

// ---------------- RMSNorm (over C) + optional RoPE, in place ----------------
// one block per row; threads own float2 pairs (3 pairs each, stride 256)
__global__ __launch_bounds__(256) void k_rms_rope(float* __restrict__ X,
                                                  const float* __restrict__ w,
                                                  const float* __restrict__ freqs,
                                                  int do_rope) {
    __shared__ float rs[256];
    int row = blockIdx.x, tid = threadIdx.x;
    float* xr = X + (size_t)row * C_DIM;
    float2 vals[3];
    float ss = 0.f;
#pragma unroll
    for (int i = 0; i < 3; ++i) {
        int p = tid + 256 * i;                 // pair index 0..767
        float2 v = *(const float2*)(xr + 2 * p);
        vals[i] = v;
        ss += v.x * v.x + v.y * v.y;
    }
    rs[tid] = ss;
    __syncthreads();
    for (int st = 128; st > 0; st >>= 1) {
        if (tid < st) rs[tid] += rs[tid + st];
        __syncthreads();
    }
    float rinv = rsqrtf(rs[0] * (1.0f / C_DIM) + EPS_F);
    int f = row / (H_GRID * W_GRID);
    int rem = row % (H_GRID * W_GRID);
    int hh = rem / W_GRID, ww = rem % W_GRID;
#pragma unroll
    for (int i = 0; i < 3; ++i) {
        int p = tid + 256 * i;
        int c = 2 * p;
        float a = vals[i].x * rinv * w[c];
        float b = vals[i].y * rinv * w[c + 1];
        if (do_rope) {
            int j = p & 63;                     // pair index within head
            int idx = (j < ROPE_P0) ? f : (j < ROPE_P1) ? hh : ww;
            float cv = freqs[(idx * 64 + j) * 2 + 0];
            float sv = freqs[(idx * 64 + j) * 2 + 1];
            float na = a * cv - b * sv;
            float nb = a * sv + b * cv;
            a = na; b = nb;
        }
        *(float2*)(xr + c) = make_float2(a, b);
    }
}

// ---------------- fp32 GEMM: C[M,N] = A[M,K] @ W[K,N] + bias[N] ----------------
// BM=BN=128, BK=8, 256 threads, 8x8 microtile. N%128==0, K%8==0 guaranteed here.
__global__ __launch_bounds__(256) void k_gemm(const float* __restrict__ A,
                                              const float* __restrict__ W,
                                              const float* __restrict__ bias,
                                              float* __restrict__ C,
                                              int M, int N, int K) {
    __shared__ __align__(16) float As[8][128];   // [k][m] (transposed)
    __shared__ __align__(16) float Ws[8][128];   // [k][n]
    int tid = threadIdx.x;
    int bn = blockIdx.x * 128, bm = blockIdx.y * 128;
    int tx = tid & 15, ty = tid >> 4;
    int la_row = tid >> 1;           // 0..127
    int la_k   = (tid & 1) * 4;      // 0 or 4
    int lw_k   = tid >> 5;           // 0..7
    int lw_n   = (tid & 31) * 4;     // 0..124
    float acc[8][8] = {{0.f}};
    for (int kb = 0; kb < K; kb += 8) {
        float4 av = make_float4(0.f, 0.f, 0.f, 0.f);
        int ar = bm + la_row;
        if (ar < M) av = *(const float4*)(A + (size_t)ar * K + kb + la_k);
        float4 wv = *(const float4*)(W + (size_t)(kb + lw_k) * N + bn + lw_n);
        __syncthreads();
        As[la_k + 0][la_row] = av.x;
        As[la_k + 1][la_row] = av.y;
        As[la_k + 2][la_row] = av.z;
        As[la_k + 3][la_row] = av.w;
        *(float4*)&Ws[lw_k][lw_n] = wv;
        __syncthreads();
#pragma unroll
        for (int kk = 0; kk < 8; ++kk) {
            float a[8], b[8];
            *(float4*)(a)     = *(const float4*)&As[kk][ty * 8];
            *(float4*)(a + 4) = *(const float4*)&As[kk][ty * 8 + 4];
            *(float4*)(b)     = *(const float4*)&Ws[kk][tx * 8];
            *(float4*)(b + 4) = *(const float4*)&Ws[kk][tx * 8 + 4];
#pragma unroll
            for (int i = 0; i < 8; ++i)
#pragma unroll
                for (int j = 0; j < 8; ++j)
                    acc[i][j] += a[i] * b[j];
        }
    }
#pragma unroll
    for (int i = 0; i < 8; ++i) {
        int row = bm + ty * 8 + i;
        if (row >= M) continue;
        float* cr = C + (size_t)row * N + bn + tx * 8;
        const float* br = bias + bn + tx * 8;
        float4 o0, o1;
        o0.x = acc[i][0] + br[0]; o0.y = acc[i][1] + br[1];
        o0.z = acc[i][2] + br[2]; o0.w = acc[i][3] + br[3];
        o1.x = acc[i][4] + br[4]; o1.y = acc[i][5] + br[5];
        o1.z = acc[i][6] + br[6]; o1.w = acc[i][7] + br[7];
        *(float4*)(cr)     = o0;
        *(float4*)(cr + 4) = o1;
    }
}

// ---------------- flash-style attention (fp32, online softmax) ----------------
// Q,K,V,O: [Lq|Lk][N_HEADS*D_HEAD] row-major; block = (q-tile of 16, head)
__global__ __launch_bounds__(256) void k_attn(const float* __restrict__ Q,
                                              const float* __restrict__ K,
                                              const float* __restrict__ V,
                                              float* __restrict__ O,
                                              int Lq, int Lk) {
    __shared__ __align__(16) float Qs[16][128];
    __shared__ __align__(16) float Ks[32][128];
    __shared__ __align__(16) float Vs[32][128];
    __shared__ float S[16][32];
    __shared__ float row_m[16], row_l[16], row_a[16];
    const int CC = N_HEADS * D_HEAD;
    int tid = threadIdx.x;
    int head = blockIdx.y;
    int q0 = blockIdx.x * 16;
    // load Q tile: 2 float4 per thread
#pragma unroll
    for (int i = 0; i < 2; ++i) {
        int idx = tid * 2 + i;
        int r = idx >> 5, c4 = idx & 31;
        *(float4*)&Qs[r][c4 * 4] =
            *(const float4*)(Q + (size_t)(q0 + r) * CC + head * D_HEAD + c4 * 4);
    }
    if (tid < 16) { row_m[tid] = -1e30f; row_l[tid] = 0.f; }
    float acc[8] = {0.f};
    int sr = tid & 15;              // score row
    int sj = (tid >> 4) * 2;        // score col pair
    int orow = tid >> 4;            // output row
    int od = (tid & 15) * 8;        // output dim group
    const float scale = 0.08838834764831845f;  // 1/sqrt(128)
    __syncthreads();
    for (int kb = 0; kb < Lk; kb += 32) {
#pragma unroll
        for (int i = 0; i < 4; ++i) {
            int idx = tid * 4 + i;
            int r = idx >> 5, c4 = idx & 31;
            *(float4*)&Ks[r][c4 * 4] =
                *(const float4*)(K + (size_t)(kb + r) * CC + head * D_HEAD + c4 * 4);
            *(float4*)&Vs[r][c4 * 4] =
                *(const float4*)(V + (size_t)(kb + r) * CC + head * D_HEAD + c4 * 4);
        }
        __syncthreads();
        // scores: each thread 2 dot products of length 128
        {
            float s0 = 0.f, s1 = 0.f;
#pragma unroll
            for (int c4 = 0; c4 < 32; ++c4) {
                float4 qv = *(const float4*)&Qs[sr][c4 * 4];
                float4 k0 = *(const float4*)&Ks[sj][c4 * 4];
                float4 k1 = *(const float4*)&Ks[sj + 1][c4 * 4];
                s0 += qv.x * k0.x + qv.y * k0.y + qv.z * k0.z + qv.w * k0.w;
                s1 += qv.x * k1.x + qv.y * k1.y + qv.z * k1.z + qv.w * k1.w;
            }
            S[sr][sj]     = s0 * scale;
            S[sr][sj + 1] = s1 * scale;
        }
        __syncthreads();
        // online softmax update (16 threads, one per row)
        if (tid < 16) {
            float m_old = row_m[tid];
            float mx = m_old;
#pragma unroll
            for (int j = 0; j < 32; ++j) mx = fmaxf(mx, S[tid][j]);
            float alpha = __expf(m_old - mx);
            float sum = 0.f;
#pragma unroll
            for (int j = 0; j < 32; ++j) {
                float p = __expf(S[tid][j] - mx);
                S[tid][j] = p; sum += p;
            }
            row_m[tid] = mx;
            row_l[tid] = row_l[tid] * alpha + sum;
            row_a[tid] = alpha;
        }
        __syncthreads();
        // O += P @ V chunk
        {
            float alpha = row_a[orow];
#pragma unroll
            for (int i = 0; i < 8; ++i) acc[i] *= alpha;
            for (int j = 0; j < 32; ++j) {
                float p = S[orow][j];
                float4 v0 = *(const float4*)&Vs[j][od];
                float4 v1 = *(const float4*)&Vs[j][od + 4];
                acc[0] += p * v0.x; acc[1] += p * v0.y;
                acc[2] += p * v0.z; acc[3] += p * v0.w;
                acc[4] += p * v1.x; acc[5] += p * v1.y;
                acc[6] += p * v1.z; acc[7] += p * v1.w;
            }
        }
        __syncthreads();
    }
    float linv = 1.0f / row_l[orow];
    float* op = O + (size_t)(q0 + orow) * CC + head * D_HEAD + od;
    float4 o0, o1;
    o0.x = acc[0] * linv; o0.y = acc[1] * linv; o0.z = acc[2] * linv; o0.w = acc[3] * linv;
    o1.x = acc[4] * linv; o1.y = acc[5] * linv; o1.z = acc[6] * linv; o1.w = acc[7] * linv;
    *(float4*)(op)     = o0;
    *(float4*)(op + 4) = o1;
}

// ---------------- host launch ----------------
extern "C" void kernel_launch(void* const* d_in, const int* in_sizes, int n_in,
                              void* d_out, int out_size, void* d_ws, size_t ws_size,
                              hipStream_t stream) {
    const float* x          = (const float*)d_in[0];
    const float* e          = (const float*)d_in[1];
    const float* context    = (const float*)d_in[2];
    const float* freqs      = (const float*)d_in[3];
    // d_in[4] seq_lens, d_in[5] context_lens, d_in[6] grid_sizes: fixed constants
    const float* modulation = (const float*)d_in[7];
    const float* sa_q_w = (const float*)d_in[8];
    const float* sa_q_b = (const float*)d_in[9];
    const float* sa_k_w = (const float*)d_in[10];
    const float* sa_k_b = (const float*)d_in[11];
    const float* sa_v_w = (const float*)d_in[12];
    const float* sa_v_b = (const float*)d_in[13];
    const float* sa_o_w = (const float*)d_in[14];
    const float* sa_o_b = (const float*)d_in[15];
    const float* sa_nq  = (const float*)d_in[16];
    const float* sa_nk  = (const float*)d_in[17];
    const float* ca_q_w = (const float*)d_in[18];
    const float* ca_q_b = (const float*)d_in[19];
    const float* ca_k_w = (const float*)d_in[20];
    const float* ca_k_b = (const float*)d_in[21];
    const float* ca_v_w = (const float*)d_in[22];
    const float* ca_v_b = (const float*)d_in[23];
    const float* ca_o_w = (const float*)d_in[24];
    const float* ca_o_b = (const float*)d_in[25];
    const float* ca_nq  = (const float*)d_in[26];
    const float* ca_nk  = (const float*)d_in[27];
    const float* ffn_w1 = (const float*)d_in[28];
    const float* ffn_b1 = (const float*)d_in[29];
    const float* ffn_w2 = (const float*)d_in[30];
    const float* ffn_b2 = (const float*)d_in[31];

    // workspace layout (floats)
    float* ws = (float*)d_ws;
    const size_t LC = (size_t)L_SEQ * C_DIM;        // 3,686,400
    float* ev   = ws;                 size_t off = 6 * C_DIM;
    float* A    = ws + off;           off += LC;     // h / attn-out
    float* Bq   = ws + off;           off += LC;     // q
    float* Ck   = ws + off;           off += LC;     // k
    float* Dv   = ws + off;           off += LC;     // v
    float* Ebuf = ws + off;           off += LC;     // proj out
    float* Xcur = ws + off;           off += LC;     // running x
    float* Fbuf = ws + off;           off += (size_t)L_SEQ * FF_DIM;  // ffn hidden

    const int nLC = (int)LC;                         // 3,686,400
    const int nFF = L_SEQ * FF_DIM;                  // 21,504,000
    dim3 blk(256);
    dim3 g_gemm_cc(C_DIM / 128, (L_SEQ + 127) / 128);      // 12 x 19
    dim3 g_gemm_ctx(C_DIM / 128, L_CTX / 128);             // 12 x 4
    dim3 g_gemm_ff1(FF_DIM / 128, (L_SEQ + 127) / 128);    // 70 x 19
    dim3 g_attn(L_SEQ / 16, N_HEADS);                      // 150 x 12

    // 0. modulation vectors
    k_embed<<<dim3((6 * C_DIM + 255) / 256), blk, 0, stream>>>(modulation, e, ev, 6 * C_DIM);

    // 1. self-attention branch
    k_lnmod<<<dim3(L_SEQ), blk, 0, stream>>>(x, ev, 0, 1, A);
    k_gemm<<<g_gemm_cc, blk, 0, stream>>>(A, sa_q_w, sa_q_b, Bq, L_SEQ, C_DIM, C_DIM);
    k_rms_rope<<<dim3(L_SEQ), blk, 0, stream>>>(Bq, sa_nq, freqs, 1);
    k_gemm<<<g_gemm_cc, blk, 0, stream>>>(A, sa_k_w, sa_k_b, Ck, L_SEQ, C_DIM, C_DIM);
    k_rms_rope<<<dim3(L_SEQ), blk, 0, stream>>>(Ck, sa_nk, freqs, 1);
    k_gemm<<<g_gemm_cc, blk, 0, stream>>>(A, sa_v_w, sa_v_b, Dv, L_SEQ, C_DIM, C_DIM);
    k_attn<<<g_attn, blk, 0, stream>>>(Bq, Ck, Dv, A, L_SEQ, L_SEQ);
    k_gemm<<<g_gemm_cc, blk, 0, stream>>>(A, sa_o_w, sa_o_b, Ebuf, L_SEQ, C_DIM, C_DIM);
    k_resid<<<dim3(nLC / 256), blk, 0, stream>>>(x, Ebuf, ev, 2, Xcur, nLC);

    // 2. cross-attention branch
    k_gemm<<<g_gemm_cc, blk, 0, stream>>>(Xcur, ca_q_w, ca_q_b, Bq, L_SEQ, C_DIM, C_DIM);
    k_rms_rope<<<dim3(L_SEQ), blk, 0, stream>>>(Bq, ca_nq, freqs, 0);
    k_gemm<<<g_gemm_ctx, blk, 0, stream>>>(context, ca_k_w, ca_k_b, Ck, L_CTX, C_DIM, C_DIM);
    k_rms_rope<<<dim3(L_CTX), blk, 0, stream>>>(Ck, ca_nk, freqs, 0);
    k_gemm<<<g_gemm_ctx, blk, 0, stream>>>(context, ca_v_w, ca_v_b, Dv, L_CTX, C_DIM, C_DIM);
    k_attn<<<g_attn, blk, 0, stream>>>(Bq, Ck, Dv, A, L_SEQ, L_CTX);
    k_gemm<<<g_gemm_cc, blk, 0, stream>>>(A, ca_o_w, ca_o_b, Ebuf, L_SEQ, C_DIM, C_DIM);
    k_resid<<<dim3(nLC / 256), blk, 0, stream>>>(Xcur, Ebuf, (const float*)nullptr, -1, Xcur, nLC);

    // 3. FFN branch
    k_lnmod<<<dim3(L_SEQ), blk, 0, stream>>>(Xcur, ev, 3, 4, A);
    k_gemm<<<g_gemm_ff1, blk, 0, stream>>>(A, ffn_w1, ffn_b1, Fbuf, L_SEQ, FF_DIM, C_DIM);
    k_gelu<<<dim3(nFF / 256), blk, 0, stream>>>(Fbuf, nFF);
    k_gemm<<<g_gemm_cc, blk, 0, stream>>>(Fbuf, ffn_w2, ffn_b2, Ebuf, L_SEQ, C_DIM, FF_DIM);
    k_resid<<<dim3(nLC / 256), blk, 0, stream>>>(Xcur, Ebuf, ev, 5, (float*)d_out, nLC);
}

// Round 2
// 4934.184 us; speedup vs baseline: 1.8902x; 1.8902x over previous
//
#include <hip/hip_runtime.h>
#include <cstddef>
#include <cstdint>

// ---------------- problem constants ----------------
#define C_DIM   1536
#define L_SEQ   2400
#define L_CTX   512
#define N_HEADS 12
#define D_HEAD  128
#define FF_DIM  8960
#define F_GRID  2
#define H_GRID  30
#define W_GRID  40
#define EPS_F   1e-6f

// rope band boundaries over D/2=64 pairs: p0=22 (frame), p1=21 (height), rest (width)
#define ROPE_P0 22
#define ROPE_P1 43   // p0 + p1

typedef __attribute__((ext_vector_type(8))) short short8;   // 8 bf16 = 4 VGPRs
typedef __attribute__((ext_vector_type(4))) float f32x4;

// round-to-nearest-even fp32 -> bf16
__device__ inline unsigned short f2bf(float f) {
    union { float f; unsigned int u; } v; v.f = f;
    unsigned int r = v.u + 0x7FFF + ((v.u >> 16) & 1);
    return (unsigned short)(r >> 16);
}

// ---------------- small elementwise kernels ----------------

__global__ __launch_bounds__(256) void k_embed(const float* __restrict__ mod,
                                               const float* __restrict__ e,
                                               float* __restrict__ ev, int n) {
    int i = blockIdx.x * 256 + threadIdx.x;
    if (i < n) ev[i] = mod[i] + e[i];
}

__global__ __launch_bounds__(256) void k_resid(const float* __restrict__ a,
                                               const float* __restrict__ b,
                                               const float* __restrict__ ev, int ei,
                                               float* __restrict__ out, int n) {
    int i = blockIdx.x * 256 + threadIdx.x;
    if (i >= n) return;
    float s = (ei >= 0) ? ev[ei * C_DIM + (i % C_DIM)] : 1.0f;
    out[i] = a[i] + b[i] * s;
}

__global__ __launch_bounds__(256) void k_gelu(float* __restrict__ x, int n) {
    int i = blockIdx.x * 256 + threadIdx.x;
    if (i >= n) return;
    float v = x[i];
    float t = tanhf(0.7978845608028654f * (v + 0.044715f * v * v * v));
    x[i] = 0.5f * v * (1.0f + t);
}

// ---------------- LayerNorm + modulation ----------------
__global__ __launch_bounds__(256) void k_lnmod(const float* __restrict__ X,
                                               const float* __restrict__ ev,
                                               int i0, int i1,
                                               float* __restrict__ H) {
    __shared__ float rs[256];
    __shared__ float rs2[256];
    int row = blockIdx.x, tid = threadIdx.x;
    const float* xr = X + (size_t)row * C_DIM;
    float vals[6];
    float s = 0.f, s2 = 0.f;
#pragma unroll
    for (int i = 0; i < 6; ++i) {
        float v = xr[tid + 256 * i];
        vals[i] = v; s += v; s2 += v * v;
    }
    rs[tid] = s; rs2[tid] = s2;
    __syncthreads();
    for (int st = 128; st > 0; st >>= 1) {
        if (tid < st) { rs[tid] += rs[tid + st]; rs2[tid] += rs2[tid + st]; }
        __syncthreads();
    }
    float mean = rs[0] * (1.0f / C_DIM);
    float var  = rs2[0] * (1.0f / C_DIM) - mean * mean;
    float rinv = rsqrtf(var + EPS_F);
    const float* E0 = ev + (size_t)i0 * C_DIM;
    const float* E1 = ev + (size_t)i1 * C_DIM;
    float* hr = H + (size_t)row * C_DIM;
#pragma unroll
    for (int i = 0; i < 6; ++i) {
        int c = tid + 256 * i;
        hr[c] = E0[c] + (vals[i] - mean) * rinv * (1.0f + E1[c]);
    }
}

// ---------------- RMSNorm + optional RoPE -> bf16 output ----------------
// one block per row; outscale folds the attention softmax scale into Q
__global__ __launch_bounds__(256) void k_rms_rope_bf16(const float* __restrict__ X,
                                                       const float* __restrict__ w,
                                                       const float* __restrict__ freqs,
                                                       int do_rope, float outscale,
                                                       unsigned short* __restrict__ Y) {
    __shared__ float rs[256];
    int row = blockIdx.x, tid = threadIdx.x;
    const float* xr = X + (size_t)row * C_DIM;
    float2 vals[3];
    float ss = 0.f;
#pragma unroll
    for (int i = 0; i < 3; ++i) {
        int p = tid + 256 * i;                 // pair index 0..767
        float2 v = *(const float2*)(xr + 2 * p);
        vals[i] = v;
        ss += v.x * v.x + v.y * v.y;
    }
    rs[tid] = ss;
    __syncthreads();
    for (int st = 128; st > 0; st >>= 1) {
        if (tid < st) rs[tid] += rs[tid + st];
        __syncthreads();
    }
    float rinv = rsqrtf(rs[0] * (1.0f / C_DIM) + EPS_F);
    int f = row / (H_GRID * W_GRID);
    int rem = row % (H_GRID * W_GRID);
    int hh = rem / W_GRID, ww = rem % W_GRID;
    unsigned short* yr = Y + (size_t)row * C_DIM;
#pragma unroll
    for (int i = 0; i < 3; ++i) {
        int p = tid + 256 * i;
        int c = 2 * p;
        float a = vals[i].x * rinv * w[c];
        float b = vals[i].y * rinv * w[c + 1];
        if (do_rope) {
            int j = p & 63;                     // pair index within head
            int idx = (j < ROPE_P0) ? f : (j < ROPE_P1) ? hh : ww;
            float cv = freqs[(idx * 64 + j) * 2 + 0];
            float sv = freqs[(idx * 64 + j) * 2 + 1];
            float na = a * cv - b * sv;
            float nb = a * sv + b * cv;
            a = na; b = nb;
        }
        a *= outscale; b *= outscale;
        unsigned int pk = (unsigned int)f2bf(a) | ((unsigned int)f2bf(b) << 16);
        *(unsigned int*)(yr + c) = pk;
    }
}

// ---------------- V transpose: fp32 [Lk][12*128] -> bf16 [12][128][Lk] ----------------
__global__ __launch_bounds__(256) void k_vt(const float* __restrict__ V,
                                            unsigned short* __restrict__ Vt, int Lk) {
    __shared__ float tile[32][33];
    int k0 = blockIdx.x * 32, h = blockIdx.y, d0 = blockIdx.z * 32;
    int t = threadIdx.x;
    int k = t >> 3, d4 = (t & 7) * 4;
    float4 v = *(const float4*)(V + (size_t)(k0 + k) * C_DIM + h * D_HEAD + d0 + d4);
    tile[k][d4 + 0] = v.x; tile[k][d4 + 1] = v.y;
    tile[k][d4 + 2] = v.z; tile[k][d4 + 3] = v.w;
    __syncthreads();
    int d = t >> 3, k4 = (t & 7) * 4;
    uint2 o;
    o.x = (unsigned int)f2bf(tile[k4 + 0][d]) | ((unsigned int)f2bf(tile[k4 + 1][d]) << 16);
    o.y = (unsigned int)f2bf(tile[k4 + 2][d]) | ((unsigned int)f2bf(tile[k4 + 3][d]) << 16);
    *(uint2*)(Vt + (size_t)(h * D_HEAD + d0 + d) * Lk + k0 + k4) = o;
}

// ---------------- MFMA flash attention ----------------
// Qb,Kb: bf16 [L][12*128] (Q pre-scaled by 1/sqrt(D)); Vt: bf16 [12][128][Lk]
// O: fp32 [Lq][12*128]. Block = 4 waves, each wave owns 16 q rows; grid (ceil(Lq/64), 12)
__global__ __launch_bounds__(256) void k_attn_mfma(const unsigned short* __restrict__ Qb,
                                                   const unsigned short* __restrict__ Kb,
                                                   const unsigned short* __restrict__ Vt,
                                                   float* __restrict__ O,
                                                   int Lq, int Lk) {
    __shared__ __align__(16) unsigned short Ks[32][136];   // +8 pad: B-frag reads 2-way
    __shared__ __align__(16) unsigned short Vs[128][40];   // V^T chunk [d][k], +8 pad
    __shared__ __align__(16) unsigned short Ps[4][16][40]; // per-wave P, C->A transform
    const int tid = threadIdx.x;
    const int w = tid >> 6, lane = tid & 63;
    const int ln = lane & 15, lq = lane >> 4;   // col-in-tile / quad
    const int h = blockIdx.y;
    const int q0 = blockIdx.x * 64 + w * 16;
    int qrow = q0 + ln; if (qrow >= Lq) qrow = Lq - 1;
    // A-fragments of Q (row m=ln, k = c*32 + lq*8 + j), kept in registers
    short8 qf[4];
#pragma unroll
    for (int c = 0; c < 4; ++c)
        qf[c] = *(const short8*)(Qb + (size_t)qrow * C_DIM + h * D_HEAD + c * 32 + lq * 8);
    f32x4 oacc[8];
#pragma unroll
    for (int t = 0; t < 8; ++t) oacc[t] = (f32x4){0.f, 0.f, 0.f, 0.f};
    float m_run[4] = {-3e38f, -3e38f, -3e38f, -3e38f};
    float l_run[4] = {0.f, 0.f, 0.f, 0.f};
    const float LOG2E = 1.4426950408889634f;

    for (int kb = 0; kb < Lk; kb += 32) {
        __syncthreads();
        // cooperative staging: K chunk (32x128) and V^T chunk (128x32), bf16x8 vectors
#pragma unroll
        for (int i = 0; i < 2; ++i) {
            int id = tid + i * 256;
            int r = id >> 4, c = id & 15;
            *(uint4*)&Ks[r][c * 8] =
                *(const uint4*)(Kb + (size_t)(kb + r) * C_DIM + h * D_HEAD + c * 8);
            int d = id >> 2, c2 = id & 3;
            *(uint4*)&Vs[d][c2 * 8] =
                *(const uint4*)(Vt + (size_t)(h * D_HEAD + d) * Lk + kb + c2 * 8);
        }
        __syncthreads();
        // S = Q K^T : two 16-col tiles (k rows 0..15, 16..31), 4 d-chunks each
        f32x4 c0 = (f32x4){0.f, 0.f, 0.f, 0.f};
        f32x4 c1 = (f32x4){0.f, 0.f, 0.f, 0.f};
#pragma unroll
        for (int c = 0; c < 4; ++c) {
            short8 b0 = *(const short8*)&Ks[ln][c * 32 + lq * 8];
            short8 b1 = *(const short8*)&Ks[16 + ln][c * 32 + lq * 8];
            c0 = __builtin_amdgcn_mfma_f32_16x16x32_bf16(qf[c], b0, c0, 0, 0, 0);
            c1 = __builtin_amdgcn_mfma_f32_16x16x32_bf16(qf[c], b1, c1, 0, 0, 0);
        }
        // online softmax: C layout row = lq*4+reg, col = ln (+16 for c1)
        float alpha[4];
#pragma unroll
        for (int r = 0; r < 4; ++r) {
            float mx = fmaxf(c0[r], c1[r]);
            mx = fmaxf(mx, __shfl_xor(mx, 1));
            mx = fmaxf(mx, __shfl_xor(mx, 2));
            mx = fmaxf(mx, __shfl_xor(mx, 4));
            mx = fmaxf(mx, __shfl_xor(mx, 8));
            float mn = fmaxf(m_run[r], mx);
            alpha[r] = exp2f((m_run[r] - mn) * LOG2E);
            float p0 = exp2f((c0[r] - mn) * LOG2E);
            float p1 = exp2f((c1[r] - mn) * LOG2E);
            float s = p0 + p1;
            s += __shfl_xor(s, 1);
            s += __shfl_xor(s, 2);
            s += __shfl_xor(s, 4);
            s += __shfl_xor(s, 8);
            l_run[r] = l_run[r] * alpha[r] + s;
            m_run[r] = mn;
            Ps[w][lq * 4 + r][ln] = f2bf(p0);
            Ps[w][lq * 4 + r][16 + ln] = f2bf(p1);
        }
#pragma unroll
        for (int t = 0; t < 8; ++t)
#pragma unroll
            for (int r = 0; r < 4; ++r) oacc[t][r] *= alpha[r];
        // P back as A-fragment (wave-private LDS; in-wave ds ordering)
        short8 pa = *(const short8*)&Ps[w][ln][lq * 8];
        // O += P @ V : 8 d-tiles of 16 cols, one MFMA each (K=32)
#pragma unroll
        for (int t = 0; t < 8; ++t) {
            short8 bv = *(const short8*)&Vs[t * 16 + ln][lq * 8];
            oacc[t] = __builtin_amdgcn_mfma_f32_16x16x32_bf16(pa, bv, oacc[t], 0, 0, 0);
        }
    }
    float linv[4];
#pragma unroll
    for (int r = 0; r < 4; ++r) linv[r] = 1.0f / l_run[r];
#pragma unroll
    for (int t = 0; t < 8; ++t)
#pragma unroll
        for (int r = 0; r < 4; ++r) {
            int row = q0 + lq * 4 + r;
            if (row < Lq)
                O[(size_t)row * C_DIM + h * D_HEAD + t * 16 + ln] = oacc[t][r] * linv[r];
        }
}

// ---------------- fp32 GEMM: C[M,N] = A[M,K] @ W[K,N] + bias[N] ----------------
__global__ __launch_bounds__(256) void k_gemm(const float* __restrict__ A,
                                              const float* __restrict__ W,
                                              const float* __restrict__ bias,
                                              float* __restrict__ C,
                                              int M, int N, int K) {
    __shared__ __align__(16) float As[8][128];
    __shared__ __align__(16) float Ws[8][128];
    int tid = threadIdx.x;
    int bn = blockIdx.x * 128, bm = blockIdx.y * 128;
    int tx = tid & 15, ty = tid >> 4;
    int la_row = tid >> 1;
    int la_k   = (tid & 1) * 4;
    int lw_k   = tid >> 5;
    int lw_n   = (tid & 31) * 4;
    float acc[8][8] = {{0.f}};
    for (int kb = 0; kb < K; kb += 8) {
        float4 av = make_float4(0.f, 0.f, 0.f, 0.f);
        int ar = bm + la_row;
        if (ar < M) av = *(const float4*)(A + (size_t)ar * K + kb + la_k);
        float4 wv = *(const float4*)(W + (size_t)(kb + lw_k) * N + bn + lw_n);
        __syncthreads();
        As[la_k + 0][la_row] = av.x;
        As[la_k + 1][la_row] = av.y;
        As[la_k + 2][la_row] = av.z;
        As[la_k + 3][la_row] = av.w;
        *(float4*)&Ws[lw_k][lw_n] = wv;
        __syncthreads();
#pragma unroll
        for (int kk = 0; kk < 8; ++kk) {
            float a[8], b[8];
            *(float4*)(a)     = *(const float4*)&As[kk][ty * 8];
            *(float4*)(a + 4) = *(const float4*)&As[kk][ty * 8 + 4];
            *(float4*)(b)     = *(const float4*)&Ws[kk][tx * 8];
            *(float4*)(b + 4) = *(const float4*)&Ws[kk][tx * 8 + 4];
#pragma unroll
            for (int i = 0; i < 8; ++i)
#pragma unroll
                for (int j = 0; j < 8; ++j)
                    acc[i][j] += a[i] * b[j];
        }
    }
#pragma unroll
    for (int i = 0; i < 8; ++i) {
        int row = bm + ty * 8 + i;
        if (row >= M) continue;
        float* cr = C + (size_t)row * N + bn + tx * 8;
        const float* br = bias + bn + tx * 8;
        float4 o0, o1;
        o0.x = acc[i][0] + br[0]; o0.y = acc[i][1] + br[1];
        o0.z = acc[i][2] + br[2]; o0.w = acc[i][3] + br[3];
        o1.x = acc[i][4] + br[4]; o1.y = acc[i][5] + br[5];
        o1.z = acc[i][6] + br[6]; o1.w = acc[i][7] + br[7];
        *(float4*)(cr)     = o0;
        *(float4*)(cr + 4) = o1;
    }
}

// ---------------- host launch ----------------
extern "C" void kernel_launch(void* const* d_in, const int* in_sizes, int n_in,
                              void* d_out, int out_size, void* d_ws, size_t ws_size,
                              hipStream_t stream) {
    const float* x          = (const float*)d_in[0];
    const float* e          = (const float*)d_in[1];
    const float* context    = (const float*)d_in[2];
    const float* freqs      = (const float*)d_in[3];
    const float* modulation = (const float*)d_in[7];
    const float* sa_q_w = (const float*)d_in[8];
    const float* sa_q_b = (const float*)d_in[9];
    const float* sa_k_w = (const float*)d_in[10];
    const float* sa_k_b = (const float*)d_in[11];
    const float* sa_v_w = (const float*)d_in[12];
    const float* sa_v_b = (const float*)d_in[13];
    const float* sa_o_w = (const float*)d_in[14];
    const float* sa_o_b = (const float*)d_in[15];
    const float* sa_nq  = (const float*)d_in[16];
    const float* sa_nk  = (const float*)d_in[17];
    const float* ca_q_w = (const float*)d_in[18];
    const float* ca_q_b = (const float*)d_in[19];
    const float* ca_k_w = (const float*)d_in[20];
    const float* ca_k_b = (const float*)d_in[21];
    const float* ca_v_w = (const float*)d_in[22];
    const float* ca_v_b = (const float*)d_in[23];
    const float* ca_o_w = (const float*)d_in[24];
    const float* ca_o_b = (const float*)d_in[25];
    const float* ca_nq  = (const float*)d_in[26];
    const float* ca_nk  = (const float*)d_in[27];
    const float* ffn_w1 = (const float*)d_in[28];
    const float* ffn_b1 = (const float*)d_in[29];
    const float* ffn_w2 = (const float*)d_in[30];
    const float* ffn_b2 = (const float*)d_in[31];

    float* ws = (float*)d_ws;
    const size_t LC = (size_t)L_SEQ * C_DIM;
    float* ev   = ws;                 size_t off = 6 * C_DIM;
    float* A    = ws + off;           off += LC;
    float* Bq   = ws + off;           off += LC;
    float* Ck   = ws + off;           off += LC;
    float* Dv   = ws + off;           off += LC;
    float* Ebuf = ws + off;           off += LC;
    float* Xcur = ws + off;           off += LC;
    float* Fbuf = ws + off;           off += (size_t)L_SEQ * FF_DIM;
    // bf16 attention buffers overlay Fbuf (unused until FFN phase): 22.2 MB < 86 MB
    unsigned short* Qb = (unsigned short*)Fbuf;
    unsigned short* Kb = Qb + LC;
    unsigned short* Vt = Kb + LC;

    const int nLC = (int)LC;
    const int nFF = L_SEQ * FF_DIM;
    const float SCALE = 0.08838834764831845f;   // 1/sqrt(128)
    dim3 blk(256);
    dim3 g_gemm_cc(C_DIM / 128, (L_SEQ + 127) / 128);
    dim3 g_gemm_ctx(C_DIM / 128, L_CTX / 128);
    dim3 g_gemm_ff1(FF_DIM / 128, (L_SEQ + 127) / 128);
    dim3 g_attn((L_SEQ + 63) / 64, N_HEADS);            // 38 x 12
    dim3 g_vt_s(L_SEQ / 32, N_HEADS, 4);                // 75 x 12 x 4
    dim3 g_vt_c(L_CTX / 32, N_HEADS, 4);                // 16 x 12 x 4

    // 0. modulation vectors
    k_embed<<<dim3((6 * C_DIM + 255) / 256), blk, 0, stream>>>(modulation, e, ev, 6 * C_DIM);

    // 1. self-attention branch
    k_lnmod<<<dim3(L_SEQ), blk, 0, stream>>>(x, ev, 0, 1, A);
    k_gemm<<<g_gemm_cc, blk, 0, stream>>>(A, sa_q_w, sa_q_b, Bq, L_SEQ, C_DIM, C_DIM);
    k_rms_rope_bf16<<<dim3(L_SEQ), blk, 0, stream>>>(Bq, sa_nq, freqs, 1, SCALE, Qb);
    k_gemm<<<g_gemm_cc, blk, 0, stream>>>(A, sa_k_w, sa_k_b, Ck, L_SEQ, C_DIM, C_DIM);
    k_rms_rope_bf16<<<dim3(L_SEQ), blk, 0, stream>>>(Ck, sa_nk, freqs, 1, 1.0f, Kb);
    k_gemm<<<g_gemm_cc, blk, 0, stream>>>(A, sa_v_w, sa_v_b, Dv, L_SEQ, C_DIM, C_DIM);
    k_vt<<<g_vt_s, blk, 0, stream>>>(Dv, Vt, L_SEQ);
    k_attn_mfma<<<g_attn, blk, 0, stream>>>(Qb, Kb, Vt, A, L_SEQ, L_SEQ);
    k_gemm<<<g_gemm_cc, blk, 0, stream>>>(A, sa_o_w, sa_o_b, Ebuf, L_SEQ, C_DIM, C_DIM);
    k_resid<<<dim3(nLC / 256), blk, 0, stream>>>(x, Ebuf, ev, 2, Xcur, nLC);

    // 2. cross-attention branch
    k_gemm<<<g_gemm_cc, blk, 0, stream>>>(Xcur, ca_q_w, ca_q_b, Bq, L_SEQ, C_DIM, C_DIM);
    k_rms_rope_bf16<<<dim3(L_SEQ), blk, 0, stream>>>(Bq, ca_nq, freqs, 0, SCALE, Qb);
    k_gemm<<<g_gemm_ctx, blk, 0, stream>>>(context, ca_k_w, ca_k_b, Ck, L_CTX, C_DIM, C_DIM);
    k_rms_rope_bf16<<<dim3(L_CTX), blk, 0, stream>>>(Ck, ca_nk, freqs, 0, 1.0f, Kb);
    k_gemm<<<g_gemm_ctx, blk, 0, stream>>>(context, ca_v_w, ca_v_b, Dv, L_CTX, C_DIM, C_DIM);
    k_vt<<<g_vt_c, blk, 0, stream>>>(Dv, Vt, L_CTX);
    k_attn_mfma<<<g_attn, blk, 0, stream>>>(Qb, Kb, Vt, A, L_SEQ, L_CTX);
    k_gemm<<<g_gemm_cc, blk, 0, stream>>>(A, ca_o_w, ca_o_b, Ebuf, L_SEQ, C_DIM, C_DIM);
    k_resid<<<dim3(nLC / 256), blk, 0, stream>>>(Xcur, Ebuf, (const float*)nullptr, -1, Xcur, nLC);

    // 3. FFN branch
    k_lnmod<<<dim3(L_SEQ), blk, 0, stream>>>(Xcur, ev, 3, 4, A);
    k_gemm<<<g_gemm_ff1, blk, 0, stream>>>(A, ffn_w1, ffn_b1, Fbuf, L_SEQ, FF_DIM, C_DIM);
    k_gelu<<<dim3(nFF / 256), blk, 0, stream>>>(Fbuf, nFF);
    k_gemm<<<g_gemm_cc, blk, 0, stream>>>(Fbuf, ffn_w2, ffn_b2, Ebuf, L_SEQ, C_DIM, FF_DIM);
    k_resid<<<dim3(nLC / 256), blk, 0, stream>>>(Xcur, Ebuf, ev, 5, (float*)d_out, nLC);
}

// Round 3
// 1235.428 us; speedup vs baseline: 7.5493x; 3.9939x over previous
//
#include <hip/hip_runtime.h>
#include <cstddef>
#include <cstdint>

// ---------------- problem constants ----------------
#define C_DIM   1536
#define L_SEQ   2400
#define L_CTX   512
#define N_HEADS 12
#define D_HEAD  128
#define FF_DIM  8960
#define F_GRID  2
#define H_GRID  30
#define W_GRID  40
#define EPS_F   1e-6f

// rope band boundaries over D/2=64 pairs: p0=22 (frame), p1=21 (height), rest (width)
#define ROPE_P0 22
#define ROPE_P1 43   // p0 + p1

typedef __attribute__((ext_vector_type(8))) short short8;   // 8 bf16 = 4 VGPRs
typedef __attribute__((ext_vector_type(4))) float f32x4;

// round-to-nearest-even fp32 -> bf16
__device__ inline unsigned short f2bf(float f) {
    union { float f; unsigned int u; } v; v.f = f;
    unsigned int r = v.u + 0x7FFF + ((v.u >> 16) & 1);
    return (unsigned short)(r >> 16);
}

#define GL2LDS(gp, lp) \
    __builtin_amdgcn_global_load_lds((const __attribute__((address_space(1))) void*)(gp), \
                                     (__attribute__((address_space(3))) void*)(lp), 16, 0, 0)

// ---------------- small elementwise kernels ----------------

__global__ __launch_bounds__(256) void k_embed(const float* __restrict__ mod,
                                               const float* __restrict__ e,
                                               float* __restrict__ ev, int n) {
    int i = blockIdx.x * 256 + threadIdx.x;
    if (i < n) ev[i] = mod[i] + e[i];
}

// out = a + b * scale(ev row ei); optional bf16 secondary output. 2 elems/thread.
__global__ __launch_bounds__(256) void k_resid2(const float* __restrict__ a,
                                                const float* __restrict__ b,
                                                const float* __restrict__ ev, int ei,
                                                float* __restrict__ out,
                                                unsigned short* __restrict__ outb, int n) {
    int i = (blockIdx.x * 256 + threadIdx.x) * 2;
    if (i >= n) return;
    int c = i % C_DIM;
    float s0 = 1.f, s1 = 1.f;
    if (ei >= 0) {
        s0 = ev[ei * C_DIM + c];
        s1 = ev[ei * C_DIM + c + 1];
    }
    float2 av = *(const float2*)(a + i);
    float2 bv = *(const float2*)(b + i);
    float o0 = av.x + bv.x * s0;
    float o1 = av.y + bv.y * s1;
    *(float2*)(out + i) = make_float2(o0, o1);
    if (outb) {
        unsigned int pk = (unsigned int)f2bf(o0) | ((unsigned int)f2bf(o1) << 16);
        *(unsigned int*)(outb + i) = pk;
    }
}

// fp32 -> bf16 convert (context)
__global__ __launch_bounds__(256) void k_tobf(const float* __restrict__ X,
                                              unsigned short* __restrict__ Y, int n) {
    int i = (blockIdx.x * 256 + threadIdx.x) * 2;
    if (i >= n) return;
    float2 v = *(const float2*)(X + i);
    unsigned int pk = (unsigned int)f2bf(v.x) | ((unsigned int)f2bf(v.y) << 16);
    *(unsigned int*)(Y + i) = pk;
}

// ---------------- LayerNorm + modulation -> bf16 ----------------
__global__ __launch_bounds__(256) void k_lnmod_bf16(const float* __restrict__ X,
                                                    const float* __restrict__ ev,
                                                    int i0, int i1,
                                                    unsigned short* __restrict__ H) {
    __shared__ float rs[256];
    __shared__ float rs2[256];
    int row = blockIdx.x, tid = threadIdx.x;
    const float* xr = X + (size_t)row * C_DIM;
    float2 vals[3];
    float s = 0.f, s2 = 0.f;
#pragma unroll
    for (int i = 0; i < 3; ++i) {
        float2 v = *(const float2*)(xr + 2 * (tid + 256 * i));
        vals[i] = v;
        s += v.x + v.y; s2 += v.x * v.x + v.y * v.y;
    }
    rs[tid] = s; rs2[tid] = s2;
    __syncthreads();
    for (int st = 128; st > 0; st >>= 1) {
        if (tid < st) { rs[tid] += rs[tid + st]; rs2[tid] += rs2[tid + st]; }
        __syncthreads();
    }
    float mean = rs[0] * (1.0f / C_DIM);
    float var  = rs2[0] * (1.0f / C_DIM) - mean * mean;
    float rinv = rsqrtf(var + EPS_F);
    const float* E0 = ev + (size_t)i0 * C_DIM;
    const float* E1 = ev + (size_t)i1 * C_DIM;
    unsigned short* hr = H + (size_t)row * C_DIM;
#pragma unroll
    for (int i = 0; i < 3; ++i) {
        int c = 2 * (tid + 256 * i);
        float o0 = E0[c]     + (vals[i].x - mean) * rinv * (1.0f + E1[c]);
        float o1 = E0[c + 1] + (vals[i].y - mean) * rinv * (1.0f + E1[c + 1]);
        unsigned int pk = (unsigned int)f2bf(o0) | ((unsigned int)f2bf(o1) << 16);
        *(unsigned int*)(hr + c) = pk;
    }
}

// ---------------- RMSNorm + optional RoPE -> bf16 ----------------
__global__ __launch_bounds__(256) void k_rms_rope_bf16(const float* __restrict__ X,
                                                       const float* __restrict__ w,
                                                       const float* __restrict__ freqs,
                                                       int do_rope, float outscale,
                                                       unsigned short* __restrict__ Y) {
    __shared__ float rs[256];
    int row = blockIdx.x, tid = threadIdx.x;
    const float* xr = X + (size_t)row * C_DIM;
    float2 vals[3];
    float ss = 0.f;
#pragma unroll
    for (int i = 0; i < 3; ++i) {
        int p = tid + 256 * i;
        float2 v = *(const float2*)(xr + 2 * p);
        vals[i] = v;
        ss += v.x * v.x + v.y * v.y;
    }
    rs[tid] = ss;
    __syncthreads();
    for (int st = 128; st > 0; st >>= 1) {
        if (tid < st) rs[tid] += rs[tid + st];
        __syncthreads();
    }
    float rinv = rsqrtf(rs[0] * (1.0f / C_DIM) + EPS_F);
    int f = row / (H_GRID * W_GRID);
    int rem = row % (H_GRID * W_GRID);
    int hh = rem / W_GRID, ww = rem % W_GRID;
    unsigned short* yr = Y + (size_t)row * C_DIM;
#pragma unroll
    for (int i = 0; i < 3; ++i) {
        int p = tid + 256 * i;
        int c = 2 * p;
        float a = vals[i].x * rinv * w[c];
        float b = vals[i].y * rinv * w[c + 1];
        if (do_rope) {
            int j = p & 63;
            int idx = (j < ROPE_P0) ? f : (j < ROPE_P1) ? hh : ww;
            float cv = freqs[(idx * 64 + j) * 2 + 0];
            float sv = freqs[(idx * 64 + j) * 2 + 1];
            float na = a * cv - b * sv;
            float nb = a * sv + b * cv;
            a = na; b = nb;
        }
        a *= outscale; b *= outscale;
        unsigned int pk = (unsigned int)f2bf(a) | ((unsigned int)f2bf(b) << 16);
        *(unsigned int*)(yr + c) = pk;
    }
}

// ---------------- weight transpose: fp32 [K][N] -> bf16 [N][K] ----------------
__global__ __launch_bounds__(256) void k_wt(const float* __restrict__ W,
                                            unsigned short* __restrict__ WT,
                                            int K, int N) {
    __shared__ float tile[32][33];
    int k0 = blockIdx.x * 32, n0 = blockIdx.y * 32;
    int t = threadIdx.x;
    int r = t >> 3, c4 = (t & 7) * 4;
    float4 v = *(const float4*)(W + (size_t)(k0 + r) * N + n0 + c4);
    tile[r][c4 + 0] = v.x; tile[r][c4 + 1] = v.y;
    tile[r][c4 + 2] = v.z; tile[r][c4 + 3] = v.w;
    __syncthreads();
    int n = t >> 3, k4 = (t & 7) * 4;
    uint2 o;
    o.x = (unsigned int)f2bf(tile[k4 + 0][n]) | ((unsigned int)f2bf(tile[k4 + 1][n]) << 16);
    o.y = (unsigned int)f2bf(tile[k4 + 2][n]) | ((unsigned int)f2bf(tile[k4 + 3][n]) << 16);
    *(uint2*)(WT + (size_t)(n0 + n) * K + k0 + k4) = o;
}

// ---------------- V transpose: fp32 [Lk][12*128] -> bf16 [12][128][Lk] ----------------
__global__ __launch_bounds__(256) void k_vt(const float* __restrict__ V,
                                            unsigned short* __restrict__ Vt, int Lk) {
    __shared__ float tile[32][33];
    int k0 = blockIdx.x * 32, h = blockIdx.y, d0 = blockIdx.z * 32;
    int t = threadIdx.x;
    int k = t >> 3, d4 = (t & 7) * 4;
    float4 v = *(const float4*)(V + (size_t)(k0 + k) * C_DIM + h * D_HEAD + d0 + d4);
    tile[k][d4 + 0] = v.x; tile[k][d4 + 1] = v.y;
    tile[k][d4 + 2] = v.z; tile[k][d4 + 3] = v.w;
    __syncthreads();
    int d = t >> 3, k4 = (t & 7) * 4;
    uint2 o;
    o.x = (unsigned int)f2bf(tile[k4 + 0][d]) | ((unsigned int)f2bf(tile[k4 + 1][d]) << 16);
    o.y = (unsigned int)f2bf(tile[k4 + 2][d]) | ((unsigned int)f2bf(tile[k4 + 3][d]) << 16);
    *(uint2*)(Vt + (size_t)(h * D_HEAD + d0 + d) * Lk + k0 + k4) = o;
}

// ---------------- MFMA flash attention (bf16 in, bf16 out) ----------------
__global__ __launch_bounds__(256) void k_attn_mfma(const unsigned short* __restrict__ Qb,
                                                   const unsigned short* __restrict__ Kb,
                                                   const unsigned short* __restrict__ Vt,
                                                   unsigned short* __restrict__ O,
                                                   int Lq, int Lk) {
    __shared__ __align__(16) unsigned short Ks[32][136];
    __shared__ __align__(16) unsigned short Vs[128][40];
    __shared__ __align__(16) unsigned short Ps[4][16][40];
    const int tid = threadIdx.x;
    const int w = tid >> 6, lane = tid & 63;
    const int ln = lane & 15, lq = lane >> 4;
    const int h = blockIdx.y;
    const int q0 = blockIdx.x * 64 + w * 16;
    int qrow = q0 + ln; if (qrow >= Lq) qrow = Lq - 1;
    short8 qf[4];
#pragma unroll
    for (int c = 0; c < 4; ++c)
        qf[c] = *(const short8*)(Qb + (size_t)qrow * C_DIM + h * D_HEAD + c * 32 + lq * 8);
    f32x4 oacc[8];
#pragma unroll
    for (int t = 0; t < 8; ++t) oacc[t] = (f32x4){0.f, 0.f, 0.f, 0.f};
    float m_run[4] = {-3e38f, -3e38f, -3e38f, -3e38f};
    float l_run[4] = {0.f, 0.f, 0.f, 0.f};
    const float LOG2E = 1.4426950408889634f;

    for (int kb = 0; kb < Lk; kb += 32) {
        __syncthreads();
#pragma unroll
        for (int i = 0; i < 2; ++i) {
            int id = tid + i * 256;
            int r = id >> 4, c = id & 15;
            *(uint4*)&Ks[r][c * 8] =
                *(const uint4*)(Kb + (size_t)(kb + r) * C_DIM + h * D_HEAD + c * 8);
            int d = id >> 2, c2 = id & 3;
            *(uint4*)&Vs[d][c2 * 8] =
                *(const uint4*)(Vt + (size_t)(h * D_HEAD + d) * Lk + kb + c2 * 8);
        }
        __syncthreads();
        f32x4 c0 = (f32x4){0.f, 0.f, 0.f, 0.f};
        f32x4 c1 = (f32x4){0.f, 0.f, 0.f, 0.f};
#pragma unroll
        for (int c = 0; c < 4; ++c) {
            short8 b0 = *(const short8*)&Ks[ln][c * 32 + lq * 8];
            short8 b1 = *(const short8*)&Ks[16 + ln][c * 32 + lq * 8];
            c0 = __builtin_amdgcn_mfma_f32_16x16x32_bf16(qf[c], b0, c0, 0, 0, 0);
            c1 = __builtin_amdgcn_mfma_f32_16x16x32_bf16(qf[c], b1, c1, 0, 0, 0);
        }
        float alpha[4];
#pragma unroll
        for (int r = 0; r < 4; ++r) {
            float mx = fmaxf(c0[r], c1[r]);
            mx = fmaxf(mx, __shfl_xor(mx, 1));
            mx = fmaxf(mx, __shfl_xor(mx, 2));
            mx = fmaxf(mx, __shfl_xor(mx, 4));
            mx = fmaxf(mx, __shfl_xor(mx, 8));
            float mn = fmaxf(m_run[r], mx);
            alpha[r] = exp2f((m_run[r] - mn) * LOG2E);
            float p0 = exp2f((c0[r] - mn) * LOG2E);
            float p1 = exp2f((c1[r] - mn) * LOG2E);
            float s = p0 + p1;
            s += __shfl_xor(s, 1);
            s += __shfl_xor(s, 2);
            s += __shfl_xor(s, 4);
            s += __shfl_xor(s, 8);
            l_run[r] = l_run[r] * alpha[r] + s;
            m_run[r] = mn;
            Ps[w][lq * 4 + r][ln] = f2bf(p0);
            Ps[w][lq * 4 + r][16 + ln] = f2bf(p1);
        }
#pragma unroll
        for (int t = 0; t < 8; ++t)
#pragma unroll
            for (int r = 0; r < 4; ++r) oacc[t][r] *= alpha[r];
        short8 pa = *(const short8*)&Ps[w][ln][lq * 8];
#pragma unroll
        for (int t = 0; t < 8; ++t) {
            short8 bv = *(const short8*)&Vs[t * 16 + ln][lq * 8];
            oacc[t] = __builtin_amdgcn_mfma_f32_16x16x32_bf16(pa, bv, oacc[t], 0, 0, 0);
        }
    }
    float linv[4];
#pragma unroll
    for (int r = 0; r < 4; ++r) linv[r] = 1.0f / l_run[r];
#pragma unroll
    for (int t = 0; t < 8; ++t)
#pragma unroll
        for (int r = 0; r < 4; ++r) {
            int row = q0 + lq * 4 + r;
            if (row < Lq)
                O[(size_t)row * C_DIM + h * D_HEAD + t * 16 + ln] = f2bf(oacc[t][r] * linv[r]);
        }
}

// ---------------- bf16 MFMA GEMM (m97 recipe): C = A[M][K] @ BT[N][K]^T + bias ----------------
// 128x128 tile, BK=32, 4 waves 2x2, global_load_lds width-16 staging, flat LDS.
// gelu=0: fp32 out to Cf. gelu=1: tanh-gelu -> bf16 out to Cb.
__global__ __launch_bounds__(256) void k_gemm_bf16(const unsigned short* __restrict__ A,
                                                   const unsigned short* __restrict__ BT,
                                                   const float* __restrict__ bias,
                                                   float* __restrict__ Cf,
                                                   unsigned short* __restrict__ Cb,
                                                   int M, int N, int K, int gelu) {
    __shared__ __align__(16) unsigned short As[128 * 32];
    __shared__ __align__(16) unsigned short Bs[128 * 32];
    const int tid = threadIdx.x;
    const int lane = tid & 63;
    const int w = tid >> 6;
    const int ln = lane & 15, lq = lane >> 4;
    const int wm = w >> 1, wn = w & 1;
    const int bm = blockIdx.y * 128, bn = blockIdx.x * 128;

    // staging coordinates: id = tid (+256), row = id>>2, col8 = (id&3)*8
    int r0 = tid >> 2, c0 = (tid & 3) * 8;
    int ar0 = bm + r0;      if (ar0 >= M) ar0 = M - 1;
    int ar1 = bm + r0 + 64; if (ar1 >= M) ar1 = M - 1;
    const unsigned short* Ag0 = A + (size_t)ar0 * K + c0;
    const unsigned short* Ag1 = A + (size_t)ar1 * K + c0;
    const unsigned short* Bg0 = BT + (size_t)(bn + r0) * K + c0;
    const unsigned short* Bg1 = BT + (size_t)(bn + r0 + 64) * K + c0;
    unsigned short* Al0 = As + tid * 8;
    unsigned short* Al1 = As + 2048 + tid * 8;
    unsigned short* Bl0 = Bs + tid * 8;
    unsigned short* Bl1 = Bs + 2048 + tid * 8;

    f32x4 acc[4][4];
#pragma unroll
    for (int i = 0; i < 4; ++i)
#pragma unroll
        for (int j = 0; j < 4; ++j) acc[i][j] = (f32x4){0.f, 0.f, 0.f, 0.f};

    for (int kb = 0; kb < K; kb += 32) {
        __syncthreads();
        GL2LDS(Ag0 + kb, Al0);
        GL2LDS(Ag1 + kb, Al1);
        GL2LDS(Bg0 + kb, Bl0);
        GL2LDS(Bg1 + kb, Bl1);
        __syncthreads();
        short8 af[4], bf[4];
#pragma unroll
        for (int mi = 0; mi < 4; ++mi)
            af[mi] = *(const short8*)&As[(wm * 64 + mi * 16 + ln) * 32 + lq * 8];
#pragma unroll
        for (int ni = 0; ni < 4; ++ni)
            bf[ni] = *(const short8*)&Bs[(wn * 64 + ni * 16 + ln) * 32 + lq * 8];
#pragma unroll
        for (int mi = 0; mi < 4; ++mi)
#pragma unroll
            for (int ni = 0; ni < 4; ++ni)
                acc[mi][ni] = __builtin_amdgcn_mfma_f32_16x16x32_bf16(af[mi], bf[ni],
                                                                      acc[mi][ni], 0, 0, 0);
    }

#pragma unroll
    for (int ni = 0; ni < 4; ++ni) {
        int col = bn + wn * 64 + ni * 16 + ln;
        float bv = bias[col];
#pragma unroll
        for (int mi = 0; mi < 4; ++mi) {
#pragma unroll
            for (int r = 0; r < 4; ++r) {
                int row = bm + wm * 64 + mi * 16 + lq * 4 + r;
                if (row >= M) continue;
                float v = acc[mi][ni][r] + bv;
                if (gelu) {
                    float u = 0.7978845608028654f * (v + 0.044715f * v * v * v);
                    float ex = __expf(2.f * u);
                    float t = 1.f - 2.f / (ex + 1.f);   // tanh(u), overflow-safe
                    float g = 0.5f * v * (1.f + t);
                    Cb[(size_t)row * N + col] = f2bf(g);
                } else {
                    Cf[(size_t)row * N + col] = v;
                }
            }
        }
    }
}

// ---------------- host launch ----------------
extern "C" void kernel_launch(void* const* d_in, const int* in_sizes, int n_in,
                              void* d_out, int out_size, void* d_ws, size_t ws_size,
                              hipStream_t stream) {
    const float* x          = (const float*)d_in[0];
    const float* e          = (const float*)d_in[1];
    const float* context    = (const float*)d_in[2];
    const float* freqs      = (const float*)d_in[3];
    const float* modulation = (const float*)d_in[7];
    const float* sa_q_w = (const float*)d_in[8];
    const float* sa_q_b = (const float*)d_in[9];
    const float* sa_k_w = (const float*)d_in[10];
    const float* sa_k_b = (const float*)d_in[11];
    const float* sa_v_w = (const float*)d_in[12];
    const float* sa_v_b = (const float*)d_in[13];
    const float* sa_o_w = (const float*)d_in[14];
    const float* sa_o_b = (const float*)d_in[15];
    const float* sa_nq  = (const float*)d_in[16];
    const float* sa_nk  = (const float*)d_in[17];
    const float* ca_q_w = (const float*)d_in[18];
    const float* ca_q_b = (const float*)d_in[19];
    const float* ca_k_w = (const float*)d_in[20];
    const float* ca_k_b = (const float*)d_in[21];
    const float* ca_v_w = (const float*)d_in[22];
    const float* ca_v_b = (const float*)d_in[23];
    const float* ca_o_w = (const float*)d_in[24];
    const float* ca_o_b = (const float*)d_in[25];
    const float* ca_nq  = (const float*)d_in[26];
    const float* ca_nk  = (const float*)d_in[27];
    const float* ffn_w1 = (const float*)d_in[28];
    const float* ffn_b1 = (const float*)d_in[29];
    const float* ffn_w2 = (const float*)d_in[30];
    const float* ffn_b2 = (const float*)d_in[31];

    // ---- workspace layout (173 MB total, <= R0's 174.6 MB footprint) ----
    const size_t LC = (size_t)L_SEQ * C_DIM;            // 3,686,400
    const size_t WMAX = (size_t)C_DIM * FF_DIM;         // 13,762,560 (largest weight)
    char* p = (char*)d_ws;
    float* ev   = (float*)p;            p += 6 * C_DIM * sizeof(float);
    float* Xcur = (float*)p;            p += LC * sizeof(float);
    float* Ebuf = (float*)p;            p += LC * sizeof(float);
    float* Bq   = (float*)p;            p += LC * sizeof(float);   // Fb overlays Bq..Dv
    float* Ck   = (float*)p;            p += LC * sizeof(float);
    float* Dv   = (float*)p;            p += LC * sizeof(float);
    unsigned short* Ab = (unsigned short*)p;  p += LC * sizeof(short);  // also ctx bf16
    unsigned short* Xb = (unsigned short*)p;  p += LC * sizeof(short);
    unsigned short* Qb = (unsigned short*)p;  p += LC * sizeof(short);
    unsigned short* Kb = (unsigned short*)p;  p += LC * sizeof(short);
    unsigned short* Vt = (unsigned short*)p;  p += LC * sizeof(short);
    unsigned short* Ob = (unsigned short*)p;  p += LC * sizeof(short);
    unsigned short* W0 = (unsigned short*)p;  p += WMAX * sizeof(short);
    unsigned short* W1 = (unsigned short*)p;  p += WMAX * sizeof(short);
    unsigned short* Fb = (unsigned short*)Bq; // [2400][8960] bf16 = 43.0 MB over 44.2 MB
    unsigned short* Cb = Ab;                  // context bf16 (phase 2; Ab dead then)

    const int nLC = (int)LC;
    const float SCALE = 0.08838834764831845f;   // 1/sqrt(128)
    dim3 blk(256);
    dim3 g_gemm_cc(C_DIM / 128, (L_SEQ + 127) / 128);      // 12 x 19
    dim3 g_gemm_ctx(C_DIM / 128, L_CTX / 128);             // 12 x 4
    dim3 g_gemm_ff1(FF_DIM / 128, (L_SEQ + 127) / 128);    // 70 x 19
    dim3 g_attn((L_SEQ + 63) / 64, N_HEADS);               // 38 x 12
    dim3 g_vt_s(L_SEQ / 32, N_HEADS, 4);
    dim3 g_vt_c(L_CTX / 32, N_HEADS, 4);
    dim3 g_wt_cc(C_DIM / 32, C_DIM / 32);                  // 48 x 48
    dim3 g_wt_w1(C_DIM / 32, FF_DIM / 32);                 // 48 x 280
    dim3 g_wt_w2(FF_DIM / 32, C_DIM / 32);                 // 280 x 48
    dim3 g_half(nLC / 512);

    k_embed<<<dim3((6 * C_DIM + 255) / 256), blk, 0, stream>>>(modulation, e, ev, 6 * C_DIM);

    // ---- phase 1: self-attention ----
    k_wt<<<g_wt_cc, blk, 0, stream>>>(sa_q_w, W0, C_DIM, C_DIM);
    k_lnmod_bf16<<<dim3(L_SEQ), blk, 0, stream>>>(x, ev, 0, 1, Ab);
    k_gemm_bf16<<<g_gemm_cc, blk, 0, stream>>>(Ab, W0, sa_q_b, Bq, nullptr, L_SEQ, C_DIM, C_DIM, 0);
    k_wt<<<g_wt_cc, blk, 0, stream>>>(sa_k_w, W1, C_DIM, C_DIM);
    k_rms_rope_bf16<<<dim3(L_SEQ), blk, 0, stream>>>(Bq, sa_nq, freqs, 1, SCALE, Qb);
    k_gemm_bf16<<<g_gemm_cc, blk, 0, stream>>>(Ab, W1, sa_k_b, Ck, nullptr, L_SEQ, C_DIM, C_DIM, 0);
    k_wt<<<g_wt_cc, blk, 0, stream>>>(sa_v_w, W0, C_DIM, C_DIM);
    k_rms_rope_bf16<<<dim3(L_SEQ), blk, 0, stream>>>(Ck, sa_nk, freqs, 1, 1.0f, Kb);
    k_gemm_bf16<<<g_gemm_cc, blk, 0, stream>>>(Ab, W0, sa_v_b, Dv, nullptr, L_SEQ, C_DIM, C_DIM, 0);
    k_wt<<<g_wt_cc, blk, 0, stream>>>(sa_o_w, W1, C_DIM, C_DIM);
    k_vt<<<g_vt_s, blk, 0, stream>>>(Dv, Vt, L_SEQ);
    k_attn_mfma<<<g_attn, blk, 0, stream>>>(Qb, Kb, Vt, Ob, L_SEQ, L_SEQ);
    k_gemm_bf16<<<g_gemm_cc, blk, 0, stream>>>(Ob, W1, sa_o_b, Ebuf, nullptr, L_SEQ, C_DIM, C_DIM, 0);
    k_resid2<<<g_half, blk, 0, stream>>>(x, Ebuf, ev, 2, Xcur, Xb, nLC);

    // ---- phase 2: cross-attention ----
    k_wt<<<g_wt_cc, blk, 0, stream>>>(ca_q_w, W0, C_DIM, C_DIM);
    k_tobf<<<dim3(L_CTX * C_DIM / 512), blk, 0, stream>>>(context, Cb, L_CTX * C_DIM);
    k_gemm_bf16<<<g_gemm_cc, blk, 0, stream>>>(Xb, W0, ca_q_b, Bq, nullptr, L_SEQ, C_DIM, C_DIM, 0);
    k_wt<<<g_wt_cc, blk, 0, stream>>>(ca_k_w, W1, C_DIM, C_DIM);
    k_rms_rope_bf16<<<dim3(L_SEQ), blk, 0, stream>>>(Bq, ca_nq, freqs, 0, SCALE, Qb);
    k_gemm_bf16<<<g_gemm_ctx, blk, 0, stream>>>(Cb, W1, ca_k_b, Ck, nullptr, L_CTX, C_DIM, C_DIM, 0);
    k_wt<<<g_wt_cc, blk, 0, stream>>>(ca_v_w, W0, C_DIM, C_DIM);
    k_rms_rope_bf16<<<dim3(L_CTX), blk, 0, stream>>>(Ck, ca_nk, freqs, 0, 1.0f, Kb);
    k_gemm_bf16<<<g_gemm_ctx, blk, 0, stream>>>(Cb, W0, ca_v_b, Dv, nullptr, L_CTX, C_DIM, C_DIM, 0);
    k_wt<<<g_wt_cc, blk, 0, stream>>>(ca_o_w, W1, C_DIM, C_DIM);
    k_vt<<<g_vt_c, blk, 0, stream>>>(Dv, Vt, L_CTX);
    k_attn_mfma<<<g_attn, blk, 0, stream>>>(Qb, Kb, Vt, Ob, L_SEQ, L_CTX);
    k_gemm_bf16<<<g_gemm_cc, blk, 0, stream>>>(Ob, W1, ca_o_b, Ebuf, nullptr, L_SEQ, C_DIM, C_DIM, 0);
    k_resid2<<<g_half, blk, 0, stream>>>(Xcur, Ebuf, (const float*)nullptr, -1, Xcur, nullptr, nLC);

    // ---- phase 3: FFN (gelu fused into w1 GEMM epilogue) ----
    k_wt<<<g_wt_w1, blk, 0, stream>>>(ffn_w1, W0, C_DIM, FF_DIM);
    k_lnmod_bf16<<<dim3(L_SEQ), blk, 0, stream>>>(Xcur, ev, 3, 4, Ab);
    k_gemm_bf16<<<g_gemm_ff1, blk, 0, stream>>>(Ab, W0, ffn_b1, nullptr, Fb, L_SEQ, FF_DIM, C_DIM, 1);
    k_wt<<<g_wt_w2, blk, 0, stream>>>(ffn_w2, W1, FF_DIM, C_DIM);
    k_gemm_bf16<<<g_gemm_cc, blk, 0, stream>>>(Fb, W1, ffn_b2, Ebuf, nullptr, L_SEQ, C_DIM, FF_DIM, 0);
    k_resid2<<<g_half, blk, 0, stream>>>(Xcur, Ebuf, ev, 5, (float*)d_out, nullptr, nLC);
}

// Round 5
// 1121.820 us; speedup vs baseline: 8.3139x; 1.1013x over previous
//
#include <hip/hip_runtime.h>
#include <cstddef>
#include <cstdint>

// ---------------- problem constants ----------------
#define C_DIM   1536
#define L_SEQ   2400
#define L_CTX   512
#define N_HEADS 12
#define D_HEAD  128
#define FF_DIM  8960
#define F_GRID  2
#define H_GRID  30
#define W_GRID  40
#define EPS_F   1e-6f

#define ROPE_P0 22
#define ROPE_P1 43   // p0 + p1

typedef __attribute__((ext_vector_type(8))) short short8;   // 8 bf16 = 4 VGPRs
typedef __attribute__((ext_vector_type(4))) float f32x4;

__device__ inline unsigned short f2bf(float f) {
    union { float f; unsigned int u; } v; v.f = f;
    unsigned int r = v.u + 0x7FFF + ((v.u >> 16) & 1);
    return (unsigned short)(r >> 16);
}

#define GL2LDS(gp, lp) \
    __builtin_amdgcn_global_load_lds((const __attribute__((address_space(1))) void*)(gp), \
                                     (__attribute__((address_space(3))) void*)(lp), 16, 0, 0)

// ---------------- small elementwise kernels ----------------

__global__ __launch_bounds__(256) void k_embed(const float* __restrict__ mod,
                                               const float* __restrict__ e,
                                               float* __restrict__ ev, int n) {
    int i = blockIdx.x * 256 + threadIdx.x;
    if (i < n) ev[i] = mod[i] + e[i];
}

// concat up to 3 bias vectors of length ne into dst
__global__ __launch_bounds__(256) void k_catbias(float* __restrict__ dst,
                                                 const float* __restrict__ b0,
                                                 const float* __restrict__ b1,
                                                 const float* __restrict__ b2,
                                                 int ne, int n) {
    int i = blockIdx.x * 256 + threadIdx.x;
    if (i >= n) return;
    const float* s = (i < ne) ? b0 : (i < 2 * ne) ? b1 : b2;
    dst[i] = s[i % ne];
}

// C[r][c] = bias[c]  (pre-init for split-K atomic accumulation)
__global__ __launch_bounds__(256) void k_initbias(float* __restrict__ C,
                                                  const float* __restrict__ bias,
                                                  int n, int N) {
    int i4 = (blockIdx.x * 256 + threadIdx.x) * 4;
    if (i4 >= n) return;
    int col = i4 % N;
    *(float4*)(C + i4) = *(const float4*)(bias + col);
}

// out = a + b * scale(ev row ei); optional bf16 secondary output. 2 elems/thread.
__global__ __launch_bounds__(256) void k_resid2(const float* __restrict__ a,
                                                const float* __restrict__ b,
                                                const float* __restrict__ ev, int ei,
                                                float* __restrict__ out,
                                                unsigned short* __restrict__ outb, int n) {
    int i = (blockIdx.x * 256 + threadIdx.x) * 2;
    if (i >= n) return;
    int c = i % C_DIM;
    float s0 = 1.f, s1 = 1.f;
    if (ei >= 0) {
        s0 = ev[ei * C_DIM + c];
        s1 = ev[ei * C_DIM + c + 1];
    }
    float2 av = *(const float2*)(a + i);
    float2 bv = *(const float2*)(b + i);
    float o0 = av.x + bv.x * s0;
    float o1 = av.y + bv.y * s1;
    *(float2*)(out + i) = make_float2(o0, o1);
    if (outb) {
        unsigned int pk = (unsigned int)f2bf(o0) | ((unsigned int)f2bf(o1) << 16);
        *(unsigned int*)(outb + i) = pk;
    }
}

// fp32 -> bf16 convert
__global__ __launch_bounds__(256) void k_tobf(const float* __restrict__ X,
                                              unsigned short* __restrict__ Y, int n) {
    int i = (blockIdx.x * 256 + threadIdx.x) * 2;
    if (i >= n) return;
    float2 v = *(const float2*)(X + i);
    unsigned int pk = (unsigned int)f2bf(v.x) | ((unsigned int)f2bf(v.y) << 16);
    *(unsigned int*)(Y + i) = pk;
}

// ---------------- LayerNorm + modulation -> bf16 ----------------
__global__ __launch_bounds__(256) void k_lnmod_bf16(const float* __restrict__ X,
                                                    const float* __restrict__ ev,
                                                    int i0, int i1,
                                                    unsigned short* __restrict__ H) {
    __shared__ float rs[256];
    __shared__ float rs2[256];
    int row = blockIdx.x, tid = threadIdx.x;
    const float* xr = X + (size_t)row * C_DIM;
    float2 vals[3];
    float s = 0.f, s2 = 0.f;
#pragma unroll
    for (int i = 0; i < 3; ++i) {
        float2 v = *(const float2*)(xr + 2 * (tid + 256 * i));
        vals[i] = v;
        s += v.x + v.y; s2 += v.x * v.x + v.y * v.y;
    }
    rs[tid] = s; rs2[tid] = s2;
    __syncthreads();
    for (int st = 128; st > 0; st >>= 1) {
        if (tid < st) { rs[tid] += rs[tid + st]; rs2[tid] += rs2[tid + st]; }
        __syncthreads();
    }
    float mean = rs[0] * (1.0f / C_DIM);
    float var  = rs2[0] * (1.0f / C_DIM) - mean * mean;
    float rinv = rsqrtf(var + EPS_F);
    const float* E0 = ev + (size_t)i0 * C_DIM;
    const float* E1 = ev + (size_t)i1 * C_DIM;
    unsigned short* hr = H + (size_t)row * C_DIM;
#pragma unroll
    for (int i = 0; i < 3; ++i) {
        int c = 2 * (tid + 256 * i);
        float o0 = E0[c]     + (vals[i].x - mean) * rinv * (1.0f + E1[c]);
        float o1 = E0[c + 1] + (vals[i].y - mean) * rinv * (1.0f + E1[c + 1]);
        unsigned int pk = (unsigned int)f2bf(o0) | ((unsigned int)f2bf(o1) << 16);
        *(unsigned int*)(hr + c) = pk;
    }
}

// ---------------- RMSNorm + optional RoPE -> bf16 (strided input) ----------------
__global__ __launch_bounds__(256) void k_rms_rope_bf16(const float* __restrict__ X,
                                                       const float* __restrict__ w,
                                                       const float* __restrict__ freqs,
                                                       int do_rope, float outscale,
                                                       unsigned short* __restrict__ Y,
                                                       int ldx) {
    __shared__ float rs[256];
    int row = blockIdx.x, tid = threadIdx.x;
    const float* xr = X + (size_t)row * ldx;
    float2 vals[3];
    float ss = 0.f;
#pragma unroll
    for (int i = 0; i < 3; ++i) {
        int p = tid + 256 * i;
        float2 v = *(const float2*)(xr + 2 * p);
        vals[i] = v;
        ss += v.x * v.x + v.y * v.y;
    }
    rs[tid] = ss;
    __syncthreads();
    for (int st = 128; st > 0; st >>= 1) {
        if (tid < st) rs[tid] += rs[tid + st];
        __syncthreads();
    }
    float rinv = rsqrtf(rs[0] * (1.0f / C_DIM) + EPS_F);
    int f = row / (H_GRID * W_GRID);
    int rem = row % (H_GRID * W_GRID);
    int hh = rem / W_GRID, ww = rem % W_GRID;
    unsigned short* yr = Y + (size_t)row * C_DIM;
#pragma unroll
    for (int i = 0; i < 3; ++i) {
        int p = tid + 256 * i;
        int c = 2 * p;
        float a = vals[i].x * rinv * w[c];
        float b = vals[i].y * rinv * w[c + 1];
        if (do_rope) {
            int j = p & 63;
            int idx = (j < ROPE_P0) ? f : (j < ROPE_P1) ? hh : ww;
            float cv = freqs[(idx * 64 + j) * 2 + 0];
            float sv = freqs[(idx * 64 + j) * 2 + 1];
            float na = a * cv - b * sv;
            float nb = a * sv + b * cv;
            a = na; b = nb;
        }
        a *= outscale; b *= outscale;
        unsigned int pk = (unsigned int)f2bf(a) | ((unsigned int)f2bf(b) << 16);
        *(unsigned int*)(yr + c) = pk;
    }
}

// ---------------- weight transpose: fp32 [K][N] -> bf16 [N][K] ----------------
__global__ __launch_bounds__(256) void k_wt(const float* __restrict__ W,
                                            unsigned short* __restrict__ WT,
                                            int K, int N) {
    __shared__ float tile[32][33];
    int k0 = blockIdx.x * 32, n0 = blockIdx.y * 32;
    int t = threadIdx.x;
    int r = t >> 3, c4 = (t & 7) * 4;
    float4 v = *(const float4*)(W + (size_t)(k0 + r) * N + n0 + c4);
    tile[r][c4 + 0] = v.x; tile[r][c4 + 1] = v.y;
    tile[r][c4 + 2] = v.z; tile[r][c4 + 3] = v.w;
    __syncthreads();
    int n = t >> 3, k4 = (t & 7) * 4;
    uint2 o;
    o.x = (unsigned int)f2bf(tile[k4 + 0][n]) | ((unsigned int)f2bf(tile[k4 + 1][n]) << 16);
    o.y = (unsigned int)f2bf(tile[k4 + 2][n]) | ((unsigned int)f2bf(tile[k4 + 3][n]) << 16);
    *(uint2*)(WT + (size_t)(n0 + n) * K + k0 + k4) = o;
}

// ---------------- V transpose: fp32 [Lk][ldv] -> bf16 [12][128][Lk] ----------------
__global__ __launch_bounds__(256) void k_vt(const float* __restrict__ V,
                                            unsigned short* __restrict__ Vt, int Lk, int ldv) {
    __shared__ float tile[32][33];
    int k0 = blockIdx.x * 32, h = blockIdx.y, d0 = blockIdx.z * 32;
    int t = threadIdx.x;
    int k = t >> 3, d4 = (t & 7) * 4;
    float4 v = *(const float4*)(V + (size_t)(k0 + k) * ldv + h * D_HEAD + d0 + d4);
    tile[k][d4 + 0] = v.x; tile[k][d4 + 1] = v.y;
    tile[k][d4 + 2] = v.z; tile[k][d4 + 3] = v.w;
    __syncthreads();
    int d = t >> 3, k4 = (t & 7) * 4;
    uint2 o;
    o.x = (unsigned int)f2bf(tile[k4 + 0][d]) | ((unsigned int)f2bf(tile[k4 + 1][d]) << 16);
    o.y = (unsigned int)f2bf(tile[k4 + 2][d]) | ((unsigned int)f2bf(tile[k4 + 3][d]) << 16);
    *(uint2*)(Vt + (size_t)(h * D_HEAD + d0 + d) * Lk + k0 + k4) = o;
}

// ---------------- MFMA flash attention (bf16 in, bf16 out) ----------------
__global__ __launch_bounds__(256) void k_attn_mfma(const unsigned short* __restrict__ Qb,
                                                   const unsigned short* __restrict__ Kb,
                                                   const unsigned short* __restrict__ Vt,
                                                   unsigned short* __restrict__ O,
                                                   int Lq, int Lk) {
    __shared__ __align__(16) unsigned short Ks[32][136];
    __shared__ __align__(16) unsigned short Vs[128][40];
    __shared__ __align__(16) unsigned short Ps[4][16][40];
    const int tid = threadIdx.x;
    const int w = tid >> 6, lane = tid & 63;
    const int ln = lane & 15, lq = lane >> 4;
    const int h = blockIdx.y;
    const int q0 = blockIdx.x * 64 + w * 16;
    int qrow = q0 + ln; if (qrow >= Lq) qrow = Lq - 1;
    short8 qf[4];
#pragma unroll
    for (int c = 0; c < 4; ++c)
        qf[c] = *(const short8*)(Qb + (size_t)qrow * C_DIM + h * D_HEAD + c * 32 + lq * 8);
    f32x4 oacc[8];
#pragma unroll
    for (int t = 0; t < 8; ++t) oacc[t] = (f32x4){0.f, 0.f, 0.f, 0.f};
    float m_run[4] = {-3e38f, -3e38f, -3e38f, -3e38f};
    float l_run[4] = {0.f, 0.f, 0.f, 0.f};
    const float LOG2E = 1.4426950408889634f;

    for (int kb = 0; kb < Lk; kb += 32) {
        __syncthreads();
#pragma unroll
        for (int i = 0; i < 2; ++i) {
            int id = tid + i * 256;
            int r = id >> 4, c = id & 15;
            *(uint4*)&Ks[r][c * 8] =
                *(const uint4*)(Kb + (size_t)(kb + r) * C_DIM + h * D_HEAD + c * 8);
            int d = id >> 2, c2 = id & 3;
            *(uint4*)&Vs[d][c2 * 8] =
                *(const uint4*)(Vt + (size_t)(h * D_HEAD + d) * Lk + kb + c2 * 8);
        }
        __syncthreads();
        f32x4 c0 = (f32x4){0.f, 0.f, 0.f, 0.f};
        f32x4 c1 = (f32x4){0.f, 0.f, 0.f, 0.f};
#pragma unroll
        for (int c = 0; c < 4; ++c) {
            short8 b0 = *(const short8*)&Ks[ln][c * 32 + lq * 8];
            short8 b1 = *(const short8*)&Ks[16 + ln][c * 32 + lq * 8];
            c0 = __builtin_amdgcn_mfma_f32_16x16x32_bf16(qf[c], b0, c0, 0, 0, 0);
            c1 = __builtin_amdgcn_mfma_f32_16x16x32_bf16(qf[c], b1, c1, 0, 0, 0);
        }
        float alpha[4];
#pragma unroll
        for (int r = 0; r < 4; ++r) {
            float mx = fmaxf(c0[r], c1[r]);
            mx = fmaxf(mx, __shfl_xor(mx, 1));
            mx = fmaxf(mx, __shfl_xor(mx, 2));
            mx = fmaxf(mx, __shfl_xor(mx, 4));
            mx = fmaxf(mx, __shfl_xor(mx, 8));
            float mn = fmaxf(m_run[r], mx);
            alpha[r] = exp2f((m_run[r] - mn) * LOG2E);
            float p0 = exp2f((c0[r] - mn) * LOG2E);
            float p1 = exp2f((c1[r] - mn) * LOG2E);
            float s = p0 + p1;
            s += __shfl_xor(s, 1);
            s += __shfl_xor(s, 2);
            s += __shfl_xor(s, 4);
            s += __shfl_xor(s, 8);
            l_run[r] = l_run[r] * alpha[r] + s;
            m_run[r] = mn;
            Ps[w][lq * 4 + r][ln] = f2bf(p0);
            Ps[w][lq * 4 + r][16 + ln] = f2bf(p1);
        }
#pragma unroll
        for (int t = 0; t < 8; ++t)
#pragma unroll
            for (int r = 0; r < 4; ++r) oacc[t][r] *= alpha[r];
        short8 pa = *(const short8*)&Ps[w][ln][lq * 8];
#pragma unroll
        for (int t = 0; t < 8; ++t) {
            short8 bv = *(const short8*)&Vs[t * 16 + ln][lq * 8];
            oacc[t] = __builtin_amdgcn_mfma_f32_16x16x32_bf16(pa, bv, oacc[t], 0, 0, 0);
        }
    }
    float linv[4];
#pragma unroll
    for (int r = 0; r < 4; ++r) linv[r] = 1.0f / l_run[r];
#pragma unroll
    for (int t = 0; t < 8; ++t)
#pragma unroll
        for (int r = 0; r < 4; ++r) {
            int row = q0 + lq * 4 + r;
            if (row < Lq)
                O[(size_t)row * C_DIM + h * D_HEAD + t * 16 + ln] = f2bf(oacc[t][r] * linv[r]);
        }
}

// ---------------- bf16 MFMA GEMM with optional split-K ----------------
// C = A[M][K] @ BT[N][K]^T (+bias). 128x128 tile, BK=32, 4 waves 2x2,
// global_load_lds width-16 staging. blockIdx.z selects K-chunk of size Kc.
// atomic=1: atomicAdd partial into bias-pre-initialized Cf.
// gelu=1 (non-atomic): tanh-gelu -> bf16 Cb.
__global__ __launch_bounds__(256) void k_gemm_bf16(const unsigned short* __restrict__ A,
                                                   const unsigned short* __restrict__ BT,
                                                   const float* __restrict__ bias,
                                                   float* __restrict__ Cf,
                                                   unsigned short* __restrict__ Cb,
                                                   int M, int N, int K, int Kc,
                                                   int gelu, int atomic) {
    __shared__ __align__(16) unsigned short As[128 * 32];
    __shared__ __align__(16) unsigned short Bs[128 * 32];
    const int tid = threadIdx.x;
    const int lane = tid & 63;
    const int w = tid >> 6;
    const int ln = lane & 15, lq = lane >> 4;
    const int wm = w >> 1, wn = w & 1;
    const int bm = blockIdx.y * 128, bn = blockIdx.x * 128;
    const int kb0 = blockIdx.z * Kc;

    int r0 = tid >> 2, c0 = (tid & 3) * 8;
    int ar0 = bm + r0;      if (ar0 >= M) ar0 = M - 1;
    int ar1 = bm + r0 + 64; if (ar1 >= M) ar1 = M - 1;
    const unsigned short* Ag0 = A + (size_t)ar0 * K + c0;
    const unsigned short* Ag1 = A + (size_t)ar1 * K + c0;
    const unsigned short* Bg0 = BT + (size_t)(bn + r0) * K + c0;
    const unsigned short* Bg1 = BT + (size_t)(bn + r0 + 64) * K + c0;
    unsigned short* Al0 = As + tid * 8;
    unsigned short* Al1 = As + 2048 + tid * 8;
    unsigned short* Bl0 = Bs + tid * 8;
    unsigned short* Bl1 = Bs + 2048 + tid * 8;

    f32x4 acc[4][4];
#pragma unroll
    for (int i = 0; i < 4; ++i)
#pragma unroll
        for (int j = 0; j < 4; ++j) acc[i][j] = (f32x4){0.f, 0.f, 0.f, 0.f};

    for (int kb = kb0; kb < kb0 + Kc; kb += 32) {
        __syncthreads();
        GL2LDS(Ag0 + kb, Al0);
        GL2LDS(Ag1 + kb, Al1);
        GL2LDS(Bg0 + kb, Bl0);
        GL2LDS(Bg1 + kb, Bl1);
        __syncthreads();
        short8 af[4], bf[4];
#pragma unroll
        for (int mi = 0; mi < 4; ++mi)
            af[mi] = *(const short8*)&As[(wm * 64 + mi * 16 + ln) * 32 + lq * 8];
#pragma unroll
        for (int ni = 0; ni < 4; ++ni)
            bf[ni] = *(const short8*)&Bs[(wn * 64 + ni * 16 + ln) * 32 + lq * 8];
#pragma unroll
        for (int mi = 0; mi < 4; ++mi)
#pragma unroll
            for (int ni = 0; ni < 4; ++ni)
                acc[mi][ni] = __builtin_amdgcn_mfma_f32_16x16x32_bf16(af[mi], bf[ni],
                                                                      acc[mi][ni], 0, 0, 0);
    }

#pragma unroll
    for (int ni = 0; ni < 4; ++ni) {
        int col = bn + wn * 64 + ni * 16 + ln;
        float bv = atomic ? 0.f : bias[col];
#pragma unroll
        for (int mi = 0; mi < 4; ++mi) {
#pragma unroll
            for (int r = 0; r < 4; ++r) {
                int row = bm + wm * 64 + mi * 16 + lq * 4 + r;
                if (row >= M) continue;
                if (atomic) {
                    atomicAdd(Cf + (size_t)row * N + col, acc[mi][ni][r]);
                } else if (gelu) {
                    float v = acc[mi][ni][r] + bv;
                    float u = 0.7978845608028654f * (v + 0.044715f * v * v * v);
                    float ex = __expf(2.f * u);
                    float t = 1.f - 2.f / (ex + 1.f);   // tanh(u), overflow-safe
                    Cb[(size_t)row * N + col] = f2bf(0.5f * v * (1.f + t));
                } else {
                    Cf[(size_t)row * N + col] = acc[mi][ni][r] + bv;
                }
            }
        }
    }
}

// ---------------- host launch ----------------
extern "C" void kernel_launch(void* const* d_in, const int* in_sizes, int n_in,
                              void* d_out, int out_size, void* d_ws, size_t ws_size,
                              hipStream_t stream) {
    const float* x          = (const float*)d_in[0];
    const float* e          = (const float*)d_in[1];
    const float* context    = (const float*)d_in[2];
    const float* freqs      = (const float*)d_in[3];
    const float* modulation = (const float*)d_in[7];
    const float* sa_q_w = (const float*)d_in[8];
    const float* sa_q_b = (const float*)d_in[9];
    const float* sa_k_w = (const float*)d_in[10];
    const float* sa_k_b = (const float*)d_in[11];
    const float* sa_v_w = (const float*)d_in[12];
    const float* sa_v_b = (const float*)d_in[13];
    const float* sa_o_w = (const float*)d_in[14];
    const float* sa_o_b = (const float*)d_in[15];
    const float* sa_nq  = (const float*)d_in[16];
    const float* sa_nk  = (const float*)d_in[17];
    const float* ca_q_w = (const float*)d_in[18];
    const float* ca_q_b = (const float*)d_in[19];
    const float* ca_k_w = (const float*)d_in[20];
    const float* ca_k_b = (const float*)d_in[21];
    const float* ca_v_w = (const float*)d_in[22];
    const float* ca_v_b = (const float*)d_in[23];
    const float* ca_o_w = (const float*)d_in[24];
    const float* ca_o_b = (const float*)d_in[25];
    const float* ca_nq  = (const float*)d_in[26];
    const float* ca_nk  = (const float*)d_in[27];
    const float* ffn_w1 = (const float*)d_in[28];
    const float* ffn_b1 = (const float*)d_in[29];
    const float* ffn_w2 = (const float*)d_in[30];
    const float* ffn_b2 = (const float*)d_in[31];

    // ---- workspace layout (~173 MB) ----
    const size_t LC = (size_t)L_SEQ * C_DIM;            // 3,686,400
    const size_t WMAX = (size_t)C_DIM * FF_DIM;         // 13,762,560
    char* p = (char*)d_ws;
    float* ev   = (float*)p;            p += 6 * C_DIM * sizeof(float);
    float* Bcat = (float*)p;            p += 3 * C_DIM * sizeof(float);
    float* Xcur = (float*)p;            p += LC * sizeof(float);
    float* Ebuf = (float*)p;            p += LC * sizeof(float);
    float* QKV  = (float*)p;            p += 3 * LC * sizeof(float);  // fused qkv out
    unsigned short* Ab = (unsigned short*)p;  p += LC * sizeof(short);
    unsigned short* Xb = (unsigned short*)p;  p += LC * sizeof(short);
    unsigned short* Qb = (unsigned short*)p;  p += LC * sizeof(short);
    unsigned short* Kb = (unsigned short*)p;  p += LC * sizeof(short);
    unsigned short* Vt = (unsigned short*)p;  p += LC * sizeof(short);
    unsigned short* Ob = (unsigned short*)p;  p += LC * sizeof(short);
    unsigned short* W0 = (unsigned short*)p;  p += WMAX * sizeof(short);
    unsigned short* W1 = (unsigned short*)p;  p += WMAX * sizeof(short);
    unsigned short* Fb = (unsigned short*)QKV;   // [2400][8960] bf16 = 43.0 MB < 44.2 MB
    float* Pq    = QKV;                          // ca_q out [2400][1536] fp32
    float* ctxKV = QKV + LC;                     // [512][3072] fp32

    const int nLC = (int)LC;
    const float SCALE = 0.08838834764831845f;   // 1/sqrt(128)
    dim3 blk(256);
    dim3 g_qkv(4608 / 128, 19, 1);                      // 36 x 19 = 684 blocks
    dim3 g_proj_s4(C_DIM / 128, 19, 4);                 // 12 x 19 x 4 = 912 blocks
    dim3 g_ctxkv_s4(3072 / 128, L_CTX / 128, 4);        // 24 x 4 x 4 = 384 blocks
    dim3 g_ff1(FF_DIM / 128, 19, 1);                    // 70 x 19 = 1330 blocks
    dim3 g_attn((L_SEQ + 63) / 64, N_HEADS);            // 38 x 12
    dim3 g_vt_s(L_SEQ / 32, N_HEADS, 4);
    dim3 g_vt_c(L_CTX / 32, N_HEADS, 4);
    dim3 g_wt_cc(C_DIM / 32, C_DIM / 32);
    dim3 g_wt_w1(C_DIM / 32, FF_DIM / 32);
    dim3 g_wt_w2(FF_DIM / 32, C_DIM / 32);
    dim3 g_half(nLC / 512);
    dim3 g_init_cc(nLC / 1024);                         // 4 elems/thread
    dim3 g_init_kv(L_CTX * 3072 / 1024);

    k_embed<<<dim3((6 * C_DIM + 255) / 256), blk, 0, stream>>>(modulation, e, ev, 6 * C_DIM);

    // ---- phase 1: self-attention ----
    k_catbias<<<dim3((3 * C_DIM + 255) / 256), blk, 0, stream>>>(Bcat, sa_q_b, sa_k_b, sa_v_b,
                                                                 C_DIM, 3 * C_DIM);
    k_wt<<<g_wt_cc, blk, 0, stream>>>(sa_q_w, W0, C_DIM, C_DIM);
    k_wt<<<g_wt_cc, blk, 0, stream>>>(sa_k_w, W0 + (size_t)C_DIM * C_DIM, C_DIM, C_DIM);
    k_wt<<<g_wt_cc, blk, 0, stream>>>(sa_v_w, W0 + (size_t)2 * C_DIM * C_DIM, C_DIM, C_DIM);
    k_lnmod_bf16<<<dim3(L_SEQ), blk, 0, stream>>>(x, ev, 0, 1, Ab);
    k_gemm_bf16<<<g_qkv, blk, 0, stream>>>(Ab, W0, Bcat, QKV, nullptr,
                                           L_SEQ, 4608, C_DIM, C_DIM, 0, 0);
    k_wt<<<g_wt_cc, blk, 0, stream>>>(sa_o_w, W1, C_DIM, C_DIM);
    k_rms_rope_bf16<<<dim3(L_SEQ), blk, 0, stream>>>(QKV, sa_nq, freqs, 1, SCALE, Qb, 4608);
    k_rms_rope_bf16<<<dim3(L_SEQ), blk, 0, stream>>>(QKV + C_DIM, sa_nk, freqs, 1, 1.0f, Kb, 4608);
    k_vt<<<g_vt_s, blk, 0, stream>>>(QKV + 2 * C_DIM, Vt, L_SEQ, 4608);
    k_attn_mfma<<<g_attn, blk, 0, stream>>>(Qb, Kb, Vt, Ob, L_SEQ, L_SEQ);
    k_initbias<<<g_init_cc, blk, 0, stream>>>(Ebuf, sa_o_b, nLC, C_DIM);
    k_gemm_bf16<<<g_proj_s4, blk, 0, stream>>>(Ob, W1, nullptr, Ebuf, nullptr,
                                               L_SEQ, C_DIM, C_DIM, 384, 0, 1);
    k_resid2<<<g_half, blk, 0, stream>>>(x, Ebuf, ev, 2, Xcur, Xb, nLC);

    // ---- phase 2: cross-attention ----
    k_wt<<<g_wt_cc, blk, 0, stream>>>(ca_q_w, W0, C_DIM, C_DIM);
    k_wt<<<g_wt_cc, blk, 0, stream>>>(ca_k_w, W1, C_DIM, C_DIM);
    k_wt<<<g_wt_cc, blk, 0, stream>>>(ca_v_w, W1 + (size_t)C_DIM * C_DIM, C_DIM, C_DIM);
    k_tobf<<<dim3(L_CTX * C_DIM / 512), blk, 0, stream>>>(context, Ab, L_CTX * C_DIM);
    k_catbias<<<dim3((2 * C_DIM + 255) / 256), blk, 0, stream>>>(Bcat, ca_k_b, ca_v_b, nullptr,
                                                                 C_DIM, 2 * C_DIM);
    k_initbias<<<g_init_cc, blk, 0, stream>>>(Pq, ca_q_b, nLC, C_DIM);
    k_gemm_bf16<<<g_proj_s4, blk, 0, stream>>>(Xb, W0, nullptr, Pq, nullptr,
                                               L_SEQ, C_DIM, C_DIM, 384, 0, 1);
    k_initbias<<<g_init_kv, blk, 0, stream>>>(ctxKV, Bcat, L_CTX * 3072, 3072);
    k_gemm_bf16<<<g_ctxkv_s4, blk, 0, stream>>>(Ab, W1, nullptr, ctxKV, nullptr,
                                                L_CTX, 3072, C_DIM, 384, 0, 1);
    k_rms_rope_bf16<<<dim3(L_SEQ), blk, 0, stream>>>(Pq, ca_nq, freqs, 0, SCALE, Qb, C_DIM);
    k_rms_rope_bf16<<<dim3(L_CTX), blk, 0, stream>>>(ctxKV, ca_nk, freqs, 0, 1.0f, Kb, 3072);
    k_vt<<<g_vt_c, blk, 0, stream>>>(ctxKV + C_DIM, Vt, L_CTX, 3072);
    k_attn_mfma<<<g_attn, blk, 0, stream>>>(Qb, Kb, Vt, Ob, L_SEQ, L_CTX);
    k_wt<<<g_wt_cc, blk, 0, stream>>>(ca_o_w, W0, C_DIM, C_DIM);
    k_initbias<<<g_init_cc, blk, 0, stream>>>(Ebuf, ca_o_b, nLC, C_DIM);
    k_gemm_bf16<<<g_proj_s4, blk, 0, stream>>>(Ob, W0, nullptr, Ebuf, nullptr,
                                               L_SEQ, C_DIM, C_DIM, 384, 0, 1);
    k_resid2<<<g_half, blk, 0, stream>>>(Xcur, Ebuf, (const float*)nullptr, -1, Xcur, nullptr, nLC);

    // ---- phase 3: FFN ----
    k_wt<<<g_wt_w1, blk, 0, stream>>>(ffn_w1, W1, C_DIM, FF_DIM);
    k_lnmod_bf16<<<dim3(L_SEQ), blk, 0, stream>>>(Xcur, ev, 3, 4, Ab);
    k_gemm_bf16<<<g_ff1, blk, 0, stream>>>(Ab, W1, ffn_b1, nullptr, Fb,
                                           L_SEQ, FF_DIM, C_DIM, C_DIM, 1, 0);
    k_wt<<<g_wt_w2, blk, 0, stream>>>(ffn_w2, W0, FF_DIM, C_DIM);
    k_initbias<<<g_init_cc, blk, 0, stream>>>(Ebuf, ffn_b2, nLC, C_DIM);
    k_gemm_bf16<<<g_proj_s4, blk, 0, stream>>>(Fb, W0, nullptr, Ebuf, nullptr,
                                               L_SEQ, C_DIM, FF_DIM, 2240, 0, 1);
    k_resid2<<<g_half, blk, 0, stream>>>(Xcur, Ebuf, ev, 5, (float*)d_out, nullptr, nLC);
}